// Round 3
// baseline (195.623 us; speedup 1.0000x reference)
//
#include <hip/hip_runtime.h>
#include <math.h>

typedef __bf16 bf16;
typedef bf16 bf16x2 __attribute__((ext_vector_type(2)));
typedef bf16 bf16x4 __attribute__((ext_vector_type(4)));
typedef bf16 bf16x8 __attribute__((ext_vector_type(8)));
typedef float f32x4 __attribute__((ext_vector_type(4)));

constexpr int CENTER = 31;
// 0.125 (1/sqrt(64)) * log2(e): folds exp->exp2 into the Q scale.
constexpr float QSCALE = 0.125f * 1.4426950408889634f;

static __device__ __forceinline__ unsigned short f2bf_bits(float f) {
    bf16 b = (bf16)f;
    return __builtin_bit_cast(unsigned short, b);
}

static __device__ __forceinline__ float fast_exp2(float x) {
#if __has_builtin(__builtin_amdgcn_exp2f)
    return __builtin_amdgcn_exp2f(x);   // raw v_exp_f32
#else
    return exp2f(x);
#endif
}

// =====================================================================
// Kernel 0: one-shot fp32 -> bf16 conversions (unchanged).
// =====================================================================
__global__ __launch_bounds__(256)
void prep_kernel(const float* __restrict__ hid,
                 const float* __restrict__ Wq, const float* __restrict__ Wk,
                 const float* __restrict__ Wv,
                 bf16* __restrict__ hb, bf16* __restrict__ htb,
                 bf16* __restrict__ Wqb, bf16* __restrict__ Wkb,
                 bf16* __restrict__ Wvp)
{
    __shared__ __attribute__((aligned(16))) bf16 hs[64][72];

    const int t   = threadIdx.x;
    const int blk = blockIdx.x;
    const int b   = blk >> 4, kc = blk & 15;

    {
        int row = t >> 2, c4 = (t & 3) * 16;
        const float4* src = (const float4*)(hid + ((size_t)b * 1024 + kc * 64 + row) * 64 + c4);
        bf16 tmp[16];
        #pragma unroll
        for (int u = 0; u < 4; ++u) {
            float4 v = src[u];
            tmp[4*u+0] = (bf16)v.x; tmp[4*u+1] = (bf16)v.y;
            tmp[4*u+2] = (bf16)v.z; tmp[4*u+3] = (bf16)v.w;
        }
        *(int4*)&hs[row][c4]     = ((int4*)tmp)[0];
        *(int4*)&hs[row][c4 + 8] = ((int4*)tmp)[1];
        bf16* hdst = hb + ((size_t)b * 1024 + kc * 64 + row) * 64 + c4;
        *(int4*)hdst       = ((int4*)tmp)[0];
        *(int4*)(hdst + 8) = ((int4*)tmp)[1];
    }

    {
        int idx = blk * 256 + t;
        if (idx < 8192) {
            float4 vq = ((const float4*)Wq)[idx];
            float4 vk = ((const float4*)Wk)[idx];
            float4 vv = ((const float4*)Wv)[idx];
            ushort4 pq, pk2, pv;
            pq.x = f2bf_bits(vq.x); pq.y = f2bf_bits(vq.y); pq.z = f2bf_bits(vq.z); pq.w = f2bf_bits(vq.w);
            pk2.x = f2bf_bits(vk.x); pk2.y = f2bf_bits(vk.y); pk2.z = f2bf_bits(vk.z); pk2.w = f2bf_bits(vk.w);
            pv.x = f2bf_bits(vv.x); pv.y = f2bf_bits(vv.y); pv.z = f2bf_bits(vv.z); pv.w = f2bf_bits(vv.w);
            ((ushort4*)Wqb)[idx] = pq;
            ((ushort4*)Wkb)[idx] = pk2;
            int c = idx >> 7, o4 = (idx & 127) * 4;
            size_t dst = (size_t)((c >> 4) * 16 + (o4 >> 5)) * 512 + (c & 15) * 32 + (o4 & 31);
            *(ushort4*)(Wvp + dst) = pv;
        }
    }
    __syncthreads();

    {
        int d = t >> 2, p0 = (t & 3) * 16;
        ushort tmp[16];
        #pragma unroll
        for (int i = 0; i < 16; ++i)
            tmp[i] = __builtin_bit_cast(unsigned short, hs[p0 + i][d]);
        bf16* dst = htb + ((size_t)b * 64 + d) * 1024 + kc * 64 + p0;
        *(int4*)dst       = ((int4*)tmp)[0];
        *(int4*)(dst + 8) = ((int4*)tmp)[1];
    }
}

// =====================================================================
// Kernel 1: Q/K projection GEMM via MFMA.
// Q/K split across blockIdx.z (512 blocks, 2/CU).
// =====================================================================
__global__ __launch_bounds__(256)
void qkproj_kernel(const bf16* __restrict__ hb,
                   const bf16* __restrict__ Wqb, const float* __restrict__ bq,
                   const bf16* __restrict__ Wkb, const float* __restrict__ bk,
                   bf16* __restrict__ qb, bf16* __restrict__ kb)
{
    __shared__ __attribute__((aligned(16))) bf16 As[128][72];
    __shared__ __attribute__((aligned(16))) bf16 Bs[128][72];

    const int t  = threadIdx.x;
    const int pt = blockIdx.x;
    const int ot = blockIdx.y;
    const int z  = blockIdx.z;
    const int p0 = pt * 128;
    const int b  = p0 >> 10;

    const bf16* Wb        = z ? Wkb : Wqb;
    const float* bias     = z ? bk : bq;
    bf16* outp            = z ? kb : qb;
    const float scale     = z ? 1.0f : QSCALE;

    {
        int row = t >> 1, ch = (t & 1) * 32;
        const int4* asrc = (const int4*)(hb + (size_t)(p0 + row) * 64 + ch);
        const int4* bsrc = (const int4*)(Wb + (size_t)(ot * 128 + row) * 64 + ch);
        #pragma unroll
        for (int u = 0; u < 4; ++u) {
            *(int4*)&As[row][ch + u * 8] = asrc[u];
            *(int4*)&Bs[row][ch + u * 8] = bsrc[u];
        }
    }
    __syncthreads();

    const int w = t >> 6, ln = t & 63, l15 = ln & 15, quad = ln >> 4;

    bf16x8 a[2][2];
    #pragma unroll
    for (int mt = 0; mt < 2; ++mt) {
        a[mt][0] = *(const bf16x8*)&As[w * 32 + mt * 16 + l15][quad * 8];
        a[mt][1] = *(const bf16x8*)&As[w * 32 + mt * 16 + l15][32 + quad * 8];
    }

    const f32x4 z4 = {0.f, 0.f, 0.f, 0.f};
    f32x4 acc[2][8];
    #pragma unroll
    for (int mt = 0; mt < 2; ++mt)
        #pragma unroll
        for (int nt = 0; nt < 8; ++nt) acc[mt][nt] = z4;

    #pragma unroll
    for (int nt = 0; nt < 8; ++nt) {
        bf16x8 b0 = *(const bf16x8*)&Bs[nt * 16 + l15][quad * 8];
        bf16x8 b1 = *(const bf16x8*)&Bs[nt * 16 + l15][32 + quad * 8];
        #pragma unroll
        for (int mt = 0; mt < 2; ++mt) {
            acc[mt][nt] = __builtin_amdgcn_mfma_f32_16x16x32_bf16(a[mt][0], b0, acc[mt][nt], 0, 0, 0);
            acc[mt][nt] = __builtin_amdgcn_mfma_f32_16x16x32_bf16(a[mt][1], b1, acc[mt][nt], 0, 0, 0);
        }
    }

    #pragma unroll
    for (int nt = 0; nt < 8; ++nt) {
        int o = ot * 128 + nt * 16 + l15;
        float bv = bias[o];
        int hh = o >> 6, d = o & 63;
        #pragma unroll
        for (int mt = 0; mt < 2; ++mt)
            #pragma unroll
            for (int r = 0; r < 4; ++r) {
                int pos = (p0 & 1023) + w * 32 + mt * 16 + quad * 4 + r;
                float val = (acc[mt][nt][r] + bv) * scale;
                outp[(((size_t)b * 8 + hh) * 1024 + pos) * 64 + d] = (bf16)val;
            }
    }
}

// =====================================================================
// Kernel 2: positional-bias precompute via MFMA.
// sg split 8 (512 blocks, 2/CU); u-loop 2. Same math.
// =====================================================================
__global__ __launch_bounds__(256)
void bias_kernel(const bf16* __restrict__ qb,
                 const float* __restrict__ row_emb, const float* __restrict__ col_emb,
                 bf16* __restrict__ rowbias, bf16* __restrict__ colbias)
{
    __shared__ __attribute__((aligned(16))) bf16 embRs[63][40];
    __shared__ __attribute__((aligned(16))) bf16 embCs[63][40];

    const int t  = threadIdx.x;
    const int bh = blockIdx.x;
    const int sg = blockIdx.y;

    for (int i = t; i < 2016; i += 256) embRs[i >> 5][i & 31] = (bf16)row_emb[i];
    for (int i = t; i < 2016; i += 256) embCs[i >> 5][i & 31] = (bf16)col_emb[i];
    __syncthreads();

    const int w = t >> 6, ln = t & 63, l15 = ln & 15, quad = ln >> 4;

    #pragma unroll
    for (int u = 0; u < 2; ++u) {
        int s = sg * 8 + u * 4 + w;
        bool cm = s >= 32;
        int ij = cm ? s - 32 : s;

        bf16x8 a[2];
        #pragma unroll
        for (int mt = 0; mt < 2; ++mt) {
            const bf16* ap = cm
                ? qb + ((size_t)bh * 1024 + (mt * 16 + l15) * 32 + ij) * 64 + 32 + quad * 8
                : qb + ((size_t)bh * 1024 + ij * 32 + mt * 16 + l15) * 64 + quad * 8;
            a[mt] = *(const bf16x8*)ap;
        }
        bf16* ob = cm ? colbias : rowbias;

        #pragma unroll
        for (int nt = 0; nt < 2; ++nt) {
            int erow = nt * 16 + l15 + CENTER - ij;
            bf16x8 bfrag = cm ? *(const bf16x8*)&embCs[erow][quad * 8]
                              : *(const bf16x8*)&embRs[erow][quad * 8];
            #pragma unroll
            for (int mt = 0; mt < 2; ++mt) {
                f32x4 c = {0.f, 0.f, 0.f, 0.f};
                c = __builtin_amdgcn_mfma_f32_16x16x32_bf16(a[mt], bfrag, c, 0, 0, 0);
                #pragma unroll
                for (int r = 0; r < 4; ++r) {
                    int ql = mt * 16 + quad * 4 + r;
                    int qrow = cm ? ql * 32 + ij : ij * 32 + ql;
                    ob[((size_t)bh * 1024 + qrow) * 32 + nt * 16 + l15] = (bf16)c[r];
                }
            }
        }
    }
}

// =====================================================================
// Kernel 3: MFMA flash attention, TRANSPOSED dataflow.
// 64-row q-tiles -> grid (16,64) = 1024 blocks, 4 blocks/CU.
// T14 register prefetch + exp2 softmax + setprio.
// =====================================================================
__global__ __launch_bounds__(256, 4)
void attn_kernel(const bf16* __restrict__ qb, const bf16* __restrict__ kb,
                 const bf16* __restrict__ htb,
                 const bf16* __restrict__ rowbias, const bf16* __restrict__ colbias,
                 bf16* __restrict__ mixedb)
{
    __shared__ __attribute__((aligned(16))) bf16 Ks[64][72];
    __shared__ __attribute__((aligned(16))) bf16 Hts[64][72];
    __shared__ __attribute__((aligned(16))) bf16 Pp[4][16][72];

    const int t  = threadIdx.x;
    const int qt = blockIdx.x;
    const int bh = blockIdx.y;
    const int b  = bh >> 3, h = bh & 7;
    const int q0 = qt * 64;
    const int w = t >> 6, ln = t & 63, l15 = ln & 15, quad = ln >> 4;

    const int qrow = q0 + w * 16 + l15;
    const bf16* qp = qb + ((size_t)bh * 1024 + qrow) * 64;
    bf16x8 bq0 = *(const bf16x8*)(qp + quad * 8);
    bf16x8 bq1 = *(const bf16x8*)(qp + 32 + quad * 8);

    float cbv[2][4];
    #pragma unroll
    for (int par = 0; par < 2; ++par) {
        bf16x4 cv = *(const bf16x4*)(colbias + ((size_t)bh * 1024 + qrow) * 32 + par * 16 + quad * 4);
        #pragma unroll
        for (int r = 0; r < 4; ++r) cbv[par][r] = (float)cv[r];
    }
    const bf16* rbp = rowbias + ((size_t)bh * 1024 + qrow) * 32;

    const f32x4 z4 = {0.f, 0.f, 0.f, 0.f};
    f32x4 oacc[4];
    float lsum = 0.f;
    #pragma unroll
    for (int dt = 0; dt < 4; ++dt) oacc[dt] = z4;

    bf16* Pw = &Pp[w][0][0];
    const bf16* kcbase = kb + (size_t)bh * 1024 * 64;
    const bf16* hcbase = htb + (size_t)b * 64 * 1024;

    // Per-thread staging addresses (fixed across kc).
    const int srow = t >> 2, sc = (t & 3) << 4;
    const bf16* kptr = kcbase + (size_t)srow * 64 + sc;     // + kc*4096
    const bf16* hptr = hcbase + (size_t)srow * 1024 + sc;   // + kc*64

    // ---- Prologue: prefetch tile kc=0 into registers ----
    int4 kr0 = *(const int4*)(kptr);
    int4 kr1 = *(const int4*)(kptr + 8);
    int4 hr0 = *(const int4*)(hptr);
    int4 hr1 = *(const int4*)(hptr + 8);
    bf16x2 rnext = *(const bf16x2*)(rbp);

    for (int kc = 0; kc < 16; ++kc) {
        __syncthreads();                       // prior compute done reading LDS
        // ---- Commit prefetched registers to LDS ----
        *(int4*)&Ks[srow][sc]      = kr0;
        *(int4*)&Ks[srow][sc + 8]  = kr1;
        *(int4*)&Hts[srow][sc]     = hr0;
        *(int4*)&Hts[srow][sc + 8] = hr1;
        float rb0 = (float)rnext[0], rb1 = (float)rnext[1];
        __syncthreads();                       // tile kc ready

        // ---- Issue prefetch for tile kc+1 (hides under compute below) ----
        if (kc < 15) {
            const bf16* kn = kptr + (size_t)(kc + 1) * 4096;
            const bf16* hn = hptr + (size_t)(kc + 1) * 64;
            kr0 = *(const int4*)(kn);
            kr1 = *(const int4*)(kn + 8);
            hr0 = *(const int4*)(hn);
            hr1 = *(const int4*)(hn + 8);
            rnext = *(const bf16x2*)(rbp + (kc + 1) * 2);
        }

        // ---- S^T = K . Q^T ----
        f32x4 sf[4];
        #pragma unroll
        for (int kt = 0; kt < 4; ++kt) sf[kt] = z4;
        __builtin_amdgcn_s_setprio(1);
        #pragma unroll
        for (int kt = 0; kt < 4; ++kt) {
            bf16x8 aK0 = *(const bf16x8*)&Ks[kt * 16 + l15][quad * 8];
            bf16x8 aK1 = *(const bf16x8*)&Ks[kt * 16 + l15][32 + quad * 8];
            sf[kt] = __builtin_amdgcn_mfma_f32_16x16x32_bf16(aK0, bq0, sf[kt], 0, 0, 0);
            sf[kt] = __builtin_amdgcn_mfma_f32_16x16x32_bf16(aK1, bq1, sf[kt], 0, 0, 0);
        }
        __builtin_amdgcn_s_setprio(0);

        // ---- softmax numerator: P = exp2(S + rb + cb) ----
        #pragma unroll
        for (int kt = 0; kt < 4; ++kt) {
            float rbv = (kt >> 1) ? rb1 : rb0;
            ushort4 pk;
            float p0 = fast_exp2(sf[kt][0] + rbv + cbv[kt & 1][0]);
            float p1 = fast_exp2(sf[kt][1] + rbv + cbv[kt & 1][1]);
            float p2 = fast_exp2(sf[kt][2] + rbv + cbv[kt & 1][2]);
            float p3 = fast_exp2(sf[kt][3] + rbv + cbv[kt & 1][3]);
            lsum += (p0 + p1) + (p2 + p3);
            pk.x = f2bf_bits(p0); pk.y = f2bf_bits(p1);
            pk.z = f2bf_bits(p2); pk.w = f2bf_bits(p3);
            *(ushort4*)&Pw[l15 * 72 + kt * 16 + quad * 4] = pk;
        }

        // ---- O^T += Ht . P^T ----
        bf16x8 bp0 = *(const bf16x8*)&Pw[l15 * 72 + quad * 8];
        bf16x8 bp1 = *(const bf16x8*)&Pw[l15 * 72 + 32 + quad * 8];
        __builtin_amdgcn_s_setprio(1);
        #pragma unroll
        for (int dt = 0; dt < 4; ++dt) {
            bf16x8 aH0 = *(const bf16x8*)&Hts[dt * 16 + l15][quad * 8];
            bf16x8 aH1 = *(const bf16x8*)&Hts[dt * 16 + l15][32 + quad * 8];
            oacc[dt] = __builtin_amdgcn_mfma_f32_16x16x32_bf16(aH0, bp0, oacc[dt], 0, 0, 0);
            oacc[dt] = __builtin_amdgcn_mfma_f32_16x16x32_bf16(aH1, bp1, oacc[dt], 0, 0, 0);
        }
        __builtin_amdgcn_s_setprio(0);
    }

    float v = lsum;
    v += __shfl_xor(v, 16);
    v += __shfl_xor(v, 32);
    float inv = 1.0f / v;

    {
        bf16* mb = mixedb + ((size_t)b * 1024 + qrow) * 512 + h * 64;
        #pragma unroll
        for (int dt = 0; dt < 4; ++dt) {
            ushort4 pk;
            pk.x = f2bf_bits(oacc[dt][0] * inv);
            pk.y = f2bf_bits(oacc[dt][1] * inv);
            pk.z = f2bf_bits(oacc[dt][2] * inv);
            pk.w = f2bf_bits(oacc[dt][3] * inv);
            *(ushort4*)(mb + dt * 16 + quad * 4) = pk;
        }
    }
}

// =====================================================================
// Kernel 4: output projection via MFMA — zero LDS, zero barriers.
// 16-pos blocks -> 512 blocks (2/CU); single row-tile per wave.
// =====================================================================
__global__ __launch_bounds__(256)
void out_proj_kernel(const bf16* __restrict__ mixedb,
                     const bf16* __restrict__ Wvp, const float* __restrict__ bv,
                     float* __restrict__ out)
{
    const int t  = threadIdx.x;
    const int p0 = blockIdx.x * 16;
    const int w = t >> 6, ln = t & 63, l15 = ln & 15, quad = ln >> 4;

    float bvv = bv[w * 16 + l15];
    f32x4 acc = {bvv, bvv, bvv, bvv};

    const bf16* arow  = mixedb + (size_t)(p0 + l15) * 512 + quad * 8;
    const bf16* bbase = Wvp + (size_t)w * 16 * 512 + l15 * 32 + quad * 8;

    #pragma unroll
    for (int kc = 0; kc < 16; ++kc) {
        bf16x8 a0 = *(const bf16x8*)(arow + kc * 32);
        bf16x8 bfrag = *(const bf16x8*)(bbase + kc * 512);
        acc = __builtin_amdgcn_mfma_f32_16x16x32_bf16(a0, bfrag, acc, 0, 0, 0);
    }

    #pragma unroll
    for (int r = 0; r < 4; ++r)
        out[(size_t)(p0 + quad * 4 + r) * 64 + w * 16 + l15] = acc[r];
}

// =====================================================================
extern "C" void kernel_launch(void* const* d_in, const int* in_sizes, int n_in,
                              void* d_out, int out_size, void* d_ws, size_t ws_size,
                              hipStream_t stream)
{
    const float* hid     = (const float*)d_in[0];
    const float* row_emb = (const float*)d_in[1];
    const float* col_emb = (const float*)d_in[2];
    const float* Wq      = (const float*)d_in[3];
    const float* bq      = (const float*)d_in[4];
    const float* Wk      = (const float*)d_in[5];
    const float* bk      = (const float*)d_in[6];
    const float* Wv      = (const float*)d_in[7];
    const float* bv      = (const float*)d_in[8];
    float* out = (float*)d_out;

    bf16* qb      = (bf16*)d_ws;
    bf16* kb      = qb + (size_t)64 * 1024 * 64;
    bf16* htb     = kb + (size_t)64 * 1024 * 64;
    bf16* rowbias = htb + (size_t)8 * 64 * 1024;
    bf16* colbias = rowbias + (size_t)64 * 1024 * 32;
    bf16* mixedb  = colbias + (size_t)64 * 1024 * 32;
    bf16* hb      = mixedb + (size_t)8 * 1024 * 512;
    bf16* Wqb     = hb + (size_t)8 * 1024 * 64;
    bf16* Wkb     = Wqb + (size_t)512 * 64;
    bf16* Wvp     = Wkb + (size_t)512 * 64;

    prep_kernel<<<128, 256, 0, stream>>>(hid, Wq, Wk, Wv, hb, htb, Wqb, Wkb, Wvp);
    qkproj_kernel<<<dim3(64, 4, 2), 256, 0, stream>>>(hb, Wqb, bq, Wkb, bk, qb, kb);
    bias_kernel<<<dim3(64, 8), 256, 0, stream>>>(qb, row_emb, col_emb, rowbias, colbias);
    attn_kernel<<<dim3(16, 64), 256, 0, stream>>>(qb, kb, htb, rowbias, colbias, mixedb);
    out_proj_kernel<<<512, 256, 0, stream>>>(mixedb, Wvp, bv, out);
}

// Round 4
// 189.856 us; speedup vs baseline: 1.0304x; 1.0304x over previous
//
#include <hip/hip_runtime.h>
#include <math.h>

typedef __bf16 bf16;
typedef bf16 bf16x2 __attribute__((ext_vector_type(2)));
typedef bf16 bf16x4 __attribute__((ext_vector_type(4)));
typedef bf16 bf16x8 __attribute__((ext_vector_type(8)));
typedef float f32x4 __attribute__((ext_vector_type(4)));

constexpr int CENTER = 31;
// 0.125 (1/sqrt(64)) * log2(e): folds exp->exp2 into the Q scale.
constexpr float QSCALE = 0.125f * 1.4426950408889634f;

static __device__ __forceinline__ unsigned short f2bf_bits(float f) {
    bf16 b = (bf16)f;
    return __builtin_bit_cast(unsigned short, b);
}

static __device__ __forceinline__ float fast_exp2(float x) {
#if __has_builtin(__builtin_amdgcn_exp2f)
    return __builtin_amdgcn_exp2f(x);   // raw v_exp_f32
#else
    return exp2f(x);
#endif
}

// =====================================================================
// Kernel 0: one-shot fp32 -> bf16 conversions (unchanged).
// =====================================================================
__global__ __launch_bounds__(256)
void prep_kernel(const float* __restrict__ hid,
                 const float* __restrict__ Wq, const float* __restrict__ Wk,
                 const float* __restrict__ Wv,
                 bf16* __restrict__ hb, bf16* __restrict__ htb,
                 bf16* __restrict__ Wqb, bf16* __restrict__ Wkb,
                 bf16* __restrict__ Wvp)
{
    __shared__ __attribute__((aligned(16))) bf16 hs[64][72];

    const int t   = threadIdx.x;
    const int blk = blockIdx.x;
    const int b   = blk >> 4, kc = blk & 15;

    {
        int row = t >> 2, c4 = (t & 3) * 16;
        const float4* src = (const float4*)(hid + ((size_t)b * 1024 + kc * 64 + row) * 64 + c4);
        bf16 tmp[16];
        #pragma unroll
        for (int u = 0; u < 4; ++u) {
            float4 v = src[u];
            tmp[4*u+0] = (bf16)v.x; tmp[4*u+1] = (bf16)v.y;
            tmp[4*u+2] = (bf16)v.z; tmp[4*u+3] = (bf16)v.w;
        }
        *(int4*)&hs[row][c4]     = ((int4*)tmp)[0];
        *(int4*)&hs[row][c4 + 8] = ((int4*)tmp)[1];
        bf16* hdst = hb + ((size_t)b * 1024 + kc * 64 + row) * 64 + c4;
        *(int4*)hdst       = ((int4*)tmp)[0];
        *(int4*)(hdst + 8) = ((int4*)tmp)[1];
    }

    {
        int idx = blk * 256 + t;
        if (idx < 8192) {
            float4 vq = ((const float4*)Wq)[idx];
            float4 vk = ((const float4*)Wk)[idx];
            float4 vv = ((const float4*)Wv)[idx];
            ushort4 pq, pk2, pv;
            pq.x = f2bf_bits(vq.x); pq.y = f2bf_bits(vq.y); pq.z = f2bf_bits(vq.z); pq.w = f2bf_bits(vq.w);
            pk2.x = f2bf_bits(vk.x); pk2.y = f2bf_bits(vk.y); pk2.z = f2bf_bits(vk.z); pk2.w = f2bf_bits(vk.w);
            pv.x = f2bf_bits(vv.x); pv.y = f2bf_bits(vv.y); pv.z = f2bf_bits(vv.z); pv.w = f2bf_bits(vv.w);
            ((ushort4*)Wqb)[idx] = pq;
            ((ushort4*)Wkb)[idx] = pk2;
            int c = idx >> 7, o4 = (idx & 127) * 4;
            size_t dst = (size_t)((c >> 4) * 16 + (o4 >> 5)) * 512 + (c & 15) * 32 + (o4 & 31);
            *(ushort4*)(Wvp + dst) = pv;
        }
    }
    __syncthreads();

    {
        int d = t >> 2, p0 = (t & 3) * 16;
        ushort tmp[16];
        #pragma unroll
        for (int i = 0; i < 16; ++i)
            tmp[i] = __builtin_bit_cast(unsigned short, hs[p0 + i][d]);
        bf16* dst = htb + ((size_t)b * 64 + d) * 1024 + kc * 64 + p0;
        *(int4*)dst       = ((int4*)tmp)[0];
        *(int4*)(dst + 8) = ((int4*)tmp)[1];
    }
}

// =====================================================================
// Kernel 1: Q/K projection GEMM via MFMA.
// Q/K split across blockIdx.z (512 blocks, 2/CU).
// =====================================================================
__global__ __launch_bounds__(256)
void qkproj_kernel(const bf16* __restrict__ hb,
                   const bf16* __restrict__ Wqb, const float* __restrict__ bq,
                   const bf16* __restrict__ Wkb, const float* __restrict__ bk,
                   bf16* __restrict__ qb, bf16* __restrict__ kb)
{
    __shared__ __attribute__((aligned(16))) bf16 As[128][72];
    __shared__ __attribute__((aligned(16))) bf16 Bs[128][72];

    const int t  = threadIdx.x;
    const int pt = blockIdx.x;
    const int ot = blockIdx.y;
    const int z  = blockIdx.z;
    const int p0 = pt * 128;
    const int b  = p0 >> 10;

    const bf16* Wb        = z ? Wkb : Wqb;
    const float* bias     = z ? bk : bq;
    bf16* outp            = z ? kb : qb;
    const float scale     = z ? 1.0f : QSCALE;

    {
        int row = t >> 1, ch = (t & 1) * 32;
        const int4* asrc = (const int4*)(hb + (size_t)(p0 + row) * 64 + ch);
        const int4* bsrc = (const int4*)(Wb + (size_t)(ot * 128 + row) * 64 + ch);
        #pragma unroll
        for (int u = 0; u < 4; ++u) {
            *(int4*)&As[row][ch + u * 8] = asrc[u];
            *(int4*)&Bs[row][ch + u * 8] = bsrc[u];
        }
    }
    __syncthreads();

    const int w = t >> 6, ln = t & 63, l15 = ln & 15, quad = ln >> 4;

    bf16x8 a[2][2];
    #pragma unroll
    for (int mt = 0; mt < 2; ++mt) {
        a[mt][0] = *(const bf16x8*)&As[w * 32 + mt * 16 + l15][quad * 8];
        a[mt][1] = *(const bf16x8*)&As[w * 32 + mt * 16 + l15][32 + quad * 8];
    }

    const f32x4 z4 = {0.f, 0.f, 0.f, 0.f};
    f32x4 acc[2][8];
    #pragma unroll
    for (int mt = 0; mt < 2; ++mt)
        #pragma unroll
        for (int nt = 0; nt < 8; ++nt) acc[mt][nt] = z4;

    #pragma unroll
    for (int nt = 0; nt < 8; ++nt) {
        bf16x8 b0 = *(const bf16x8*)&Bs[nt * 16 + l15][quad * 8];
        bf16x8 b1 = *(const bf16x8*)&Bs[nt * 16 + l15][32 + quad * 8];
        #pragma unroll
        for (int mt = 0; mt < 2; ++mt) {
            acc[mt][nt] = __builtin_amdgcn_mfma_f32_16x16x32_bf16(a[mt][0], b0, acc[mt][nt], 0, 0, 0);
            acc[mt][nt] = __builtin_amdgcn_mfma_f32_16x16x32_bf16(a[mt][1], b1, acc[mt][nt], 0, 0, 0);
        }
    }

    #pragma unroll
    for (int nt = 0; nt < 8; ++nt) {
        int o = ot * 128 + nt * 16 + l15;
        float bv = bias[o];
        int hh = o >> 6, d = o & 63;
        #pragma unroll
        for (int mt = 0; mt < 2; ++mt)
            #pragma unroll
            for (int r = 0; r < 4; ++r) {
                int pos = (p0 & 1023) + w * 32 + mt * 16 + quad * 4 + r;
                float val = (acc[mt][nt][r] + bv) * scale;
                outp[(((size_t)b * 8 + hh) * 1024 + pos) * 64 + d] = (bf16)val;
            }
    }
}

// =====================================================================
// Kernel 2: positional-bias precompute via MFMA.
// sg split 8 (512 blocks, 2/CU); u-loop 2. Same math.
// =====================================================================
__global__ __launch_bounds__(256)
void bias_kernel(const bf16* __restrict__ qb,
                 const float* __restrict__ row_emb, const float* __restrict__ col_emb,
                 bf16* __restrict__ rowbias, bf16* __restrict__ colbias)
{
    __shared__ __attribute__((aligned(16))) bf16 embRs[63][40];
    __shared__ __attribute__((aligned(16))) bf16 embCs[63][40];

    const int t  = threadIdx.x;
    const int bh = blockIdx.x;
    const int sg = blockIdx.y;

    for (int i = t; i < 2016; i += 256) embRs[i >> 5][i & 31] = (bf16)row_emb[i];
    for (int i = t; i < 2016; i += 256) embCs[i >> 5][i & 31] = (bf16)col_emb[i];
    __syncthreads();

    const int w = t >> 6, ln = t & 63, l15 = ln & 15, quad = ln >> 4;

    #pragma unroll
    for (int u = 0; u < 2; ++u) {
        int s = sg * 8 + u * 4 + w;
        bool cm = s >= 32;
        int ij = cm ? s - 32 : s;

        bf16x8 a[2];
        #pragma unroll
        for (int mt = 0; mt < 2; ++mt) {
            const bf16* ap = cm
                ? qb + ((size_t)bh * 1024 + (mt * 16 + l15) * 32 + ij) * 64 + 32 + quad * 8
                : qb + ((size_t)bh * 1024 + ij * 32 + mt * 16 + l15) * 64 + quad * 8;
            a[mt] = *(const bf16x8*)ap;
        }
        bf16* ob = cm ? colbias : rowbias;

        #pragma unroll
        for (int nt = 0; nt < 2; ++nt) {
            int erow = nt * 16 + l15 + CENTER - ij;
            bf16x8 bfrag = cm ? *(const bf16x8*)&embCs[erow][quad * 8]
                              : *(const bf16x8*)&embRs[erow][quad * 8];
            #pragma unroll
            for (int mt = 0; mt < 2; ++mt) {
                f32x4 c = {0.f, 0.f, 0.f, 0.f};
                c = __builtin_amdgcn_mfma_f32_16x16x32_bf16(a[mt], bfrag, c, 0, 0, 0);
                #pragma unroll
                for (int r = 0; r < 4; ++r) {
                    int ql = mt * 16 + quad * 4 + r;
                    int qrow = cm ? ql * 32 + ij : ij * 32 + ql;
                    ob[((size_t)bh * 1024 + qrow) * 32 + nt * 16 + l15] = (bf16)c[r];
                }
            }
        }
    }
}

// =====================================================================
// Kernel 3: MFMA flash attention, TRANSPOSED dataflow.
// R4: XCD-clustered block swizzle (T1). 1D grid of 1024; xcd = id%8
// round-robin, so we pack all 16 q-tiles of a bh onto ONE xcd, and give
// xcd r exactly bh in [8r, 8r+8) = all heads of batch b=r. K (per-bh,
// 128KB) and Ht (per-b, 128KB) then live in that xcd's 4MB L2: working
// set 1.1MB, K/Ht fetched from HBM once instead of 16x.
// =====================================================================
__global__ __launch_bounds__(256, 4)
void attn_kernel(const bf16* __restrict__ qb, const bf16* __restrict__ kb,
                 const bf16* __restrict__ htb,
                 const bf16* __restrict__ rowbias, const bf16* __restrict__ colbias,
                 bf16* __restrict__ mixedb)
{
    __shared__ __attribute__((aligned(16))) bf16 Ks[64][72];
    __shared__ __attribute__((aligned(16))) bf16 Hts[64][72];
    __shared__ __attribute__((aligned(16))) bf16 Pp[4][16][72];

    const int t  = threadIdx.x;
    // XCD-clustered decode: id = r + 8*(bh_local*16 + qt), xcd = id%8 = r.
    const int id = blockIdx.x;
    const int r8 = id & 7;
    const int g  = id >> 3;
    const int qt = g & 15;
    const int bh = r8 * 8 + (g >> 4);
    const int b  = bh >> 3, h = bh & 7;
    const int q0 = qt * 64;
    const int w = t >> 6, ln = t & 63, l15 = ln & 15, quad = ln >> 4;

    const int qrow = q0 + w * 16 + l15;
    const bf16* qp = qb + ((size_t)bh * 1024 + qrow) * 64;
    bf16x8 bq0 = *(const bf16x8*)(qp + quad * 8);
    bf16x8 bq1 = *(const bf16x8*)(qp + 32 + quad * 8);

    float cbv[2][4];
    #pragma unroll
    for (int par = 0; par < 2; ++par) {
        bf16x4 cv = *(const bf16x4*)(colbias + ((size_t)bh * 1024 + qrow) * 32 + par * 16 + quad * 4);
        #pragma unroll
        for (int r = 0; r < 4; ++r) cbv[par][r] = (float)cv[r];
    }
    const bf16* rbp = rowbias + ((size_t)bh * 1024 + qrow) * 32;

    const f32x4 z4 = {0.f, 0.f, 0.f, 0.f};
    f32x4 oacc[4];
    float lsum = 0.f;
    #pragma unroll
    for (int dt = 0; dt < 4; ++dt) oacc[dt] = z4;

    bf16* Pw = &Pp[w][0][0];
    const bf16* kcbase = kb + (size_t)bh * 1024 * 64;
    const bf16* hcbase = htb + (size_t)b * 64 * 1024;

    // Per-thread staging addresses (fixed across kc).
    const int srow = t >> 2, sc = (t & 3) << 4;
    const bf16* kptr = kcbase + (size_t)srow * 64 + sc;     // + kc*4096
    const bf16* hptr = hcbase + (size_t)srow * 1024 + sc;   // + kc*64

    // ---- Prologue: prefetch tile kc=0 into registers ----
    int4 kr0 = *(const int4*)(kptr);
    int4 kr1 = *(const int4*)(kptr + 8);
    int4 hr0 = *(const int4*)(hptr);
    int4 hr1 = *(const int4*)(hptr + 8);
    bf16x2 rnext = *(const bf16x2*)(rbp);

    for (int kc = 0; kc < 16; ++kc) {
        __syncthreads();                       // prior compute done reading LDS
        // ---- Commit prefetched registers to LDS ----
        *(int4*)&Ks[srow][sc]      = kr0;
        *(int4*)&Ks[srow][sc + 8]  = kr1;
        *(int4*)&Hts[srow][sc]     = hr0;
        *(int4*)&Hts[srow][sc + 8] = hr1;
        float rb0 = (float)rnext[0], rb1 = (float)rnext[1];
        __syncthreads();                       // tile kc ready

        // ---- Issue prefetch for tile kc+1 (hides under compute below) ----
        if (kc < 15) {
            const bf16* kn = kptr + (size_t)(kc + 1) * 4096;
            const bf16* hn = hptr + (size_t)(kc + 1) * 64;
            kr0 = *(const int4*)(kn);
            kr1 = *(const int4*)(kn + 8);
            hr0 = *(const int4*)(hn);
            hr1 = *(const int4*)(hn + 8);
            rnext = *(const bf16x2*)(rbp + (kc + 1) * 2);
        }

        // ---- S^T = K . Q^T ----
        f32x4 sf[4];
        #pragma unroll
        for (int kt = 0; kt < 4; ++kt) sf[kt] = z4;
        __builtin_amdgcn_s_setprio(1);
        #pragma unroll
        for (int kt = 0; kt < 4; ++kt) {
            bf16x8 aK0 = *(const bf16x8*)&Ks[kt * 16 + l15][quad * 8];
            bf16x8 aK1 = *(const bf16x8*)&Ks[kt * 16 + l15][32 + quad * 8];
            sf[kt] = __builtin_amdgcn_mfma_f32_16x16x32_bf16(aK0, bq0, sf[kt], 0, 0, 0);
            sf[kt] = __builtin_amdgcn_mfma_f32_16x16x32_bf16(aK1, bq1, sf[kt], 0, 0, 0);
        }
        __builtin_amdgcn_s_setprio(0);

        // ---- softmax numerator: P = exp2(S + rb + cb) ----
        #pragma unroll
        for (int kt = 0; kt < 4; ++kt) {
            float rbv = (kt >> 1) ? rb1 : rb0;
            ushort4 pk;
            float p0 = fast_exp2(sf[kt][0] + rbv + cbv[kt & 1][0]);
            float p1 = fast_exp2(sf[kt][1] + rbv + cbv[kt & 1][1]);
            float p2 = fast_exp2(sf[kt][2] + rbv + cbv[kt & 1][2]);
            float p3 = fast_exp2(sf[kt][3] + rbv + cbv[kt & 1][3]);
            lsum += (p0 + p1) + (p2 + p3);
            pk.x = f2bf_bits(p0); pk.y = f2bf_bits(p1);
            pk.z = f2bf_bits(p2); pk.w = f2bf_bits(p3);
            *(ushort4*)&Pw[l15 * 72 + kt * 16 + quad * 4] = pk;
        }

        // ---- O^T += Ht . P^T ----
        bf16x8 bp0 = *(const bf16x8*)&Pw[l15 * 72 + quad * 8];
        bf16x8 bp1 = *(const bf16x8*)&Pw[l15 * 72 + 32 + quad * 8];
        __builtin_amdgcn_s_setprio(1);
        #pragma unroll
        for (int dt = 0; dt < 4; ++dt) {
            bf16x8 aH0 = *(const bf16x8*)&Hts[dt * 16 + l15][quad * 8];
            bf16x8 aH1 = *(const bf16x8*)&Hts[dt * 16 + l15][32 + quad * 8];
            oacc[dt] = __builtin_amdgcn_mfma_f32_16x16x32_bf16(aH0, bp0, oacc[dt], 0, 0, 0);
            oacc[dt] = __builtin_amdgcn_mfma_f32_16x16x32_bf16(aH1, bp1, oacc[dt], 0, 0, 0);
        }
        __builtin_amdgcn_s_setprio(0);
    }

    float v = lsum;
    v += __shfl_xor(v, 16);
    v += __shfl_xor(v, 32);
    float inv = 1.0f / v;

    {
        bf16* mb = mixedb + ((size_t)b * 1024 + qrow) * 512 + h * 64;
        #pragma unroll
        for (int dt = 0; dt < 4; ++dt) {
            ushort4 pk;
            pk.x = f2bf_bits(oacc[dt][0] * inv);
            pk.y = f2bf_bits(oacc[dt][1] * inv);
            pk.z = f2bf_bits(oacc[dt][2] * inv);
            pk.w = f2bf_bits(oacc[dt][3] * inv);
            *(ushort4*)(mb + dt * 16 + quad * 4) = pk;
        }
    }
}

// =====================================================================
// Kernel 4: output projection via MFMA — zero LDS, zero barriers.
// 16-pos blocks -> 512 blocks (2/CU); single row-tile per wave.
// =====================================================================
__global__ __launch_bounds__(256)
void out_proj_kernel(const bf16* __restrict__ mixedb,
                     const bf16* __restrict__ Wvp, const float* __restrict__ bv,
                     float* __restrict__ out)
{
    const int t  = threadIdx.x;
    const int p0 = blockIdx.x * 16;
    const int w = t >> 6, ln = t & 63, l15 = ln & 15, quad = ln >> 4;

    float bvv = bv[w * 16 + l15];
    f32x4 acc = {bvv, bvv, bvv, bvv};

    const bf16* arow  = mixedb + (size_t)(p0 + l15) * 512 + quad * 8;
    const bf16* bbase = Wvp + (size_t)w * 16 * 512 + l15 * 32 + quad * 8;

    #pragma unroll
    for (int kc = 0; kc < 16; ++kc) {
        bf16x8 a0 = *(const bf16x8*)(arow + kc * 32);
        bf16x8 bfrag = *(const bf16x8*)(bbase + kc * 512);
        acc = __builtin_amdgcn_mfma_f32_16x16x32_bf16(a0, bfrag, acc, 0, 0, 0);
    }

    #pragma unroll
    for (int r = 0; r < 4; ++r)
        out[(size_t)(p0 + quad * 4 + r) * 64 + w * 16 + l15] = acc[r];
}

// =====================================================================
extern "C" void kernel_launch(void* const* d_in, const int* in_sizes, int n_in,
                              void* d_out, int out_size, void* d_ws, size_t ws_size,
                              hipStream_t stream)
{
    const float* hid     = (const float*)d_in[0];
    const float* row_emb = (const float*)d_in[1];
    const float* col_emb = (const float*)d_in[2];
    const float* Wq      = (const float*)d_in[3];
    const float* bq      = (const float*)d_in[4];
    const float* Wk      = (const float*)d_in[5];
    const float* bk      = (const float*)d_in[6];
    const float* Wv      = (const float*)d_in[7];
    const float* bv      = (const float*)d_in[8];
    float* out = (float*)d_out;

    bf16* qb      = (bf16*)d_ws;
    bf16* kb      = qb + (size_t)64 * 1024 * 64;
    bf16* htb     = kb + (size_t)64 * 1024 * 64;
    bf16* rowbias = htb + (size_t)8 * 64 * 1024;
    bf16* colbias = rowbias + (size_t)64 * 1024 * 32;
    bf16* mixedb  = colbias + (size_t)64 * 1024 * 32;
    bf16* hb      = mixedb + (size_t)8 * 1024 * 512;
    bf16* Wqb     = hb + (size_t)8 * 1024 * 64;
    bf16* Wkb     = Wqb + (size_t)512 * 64;
    bf16* Wvp     = Wkb + (size_t)512 * 64;

    prep_kernel<<<128, 256, 0, stream>>>(hid, Wq, Wk, Wv, hb, htb, Wqb, Wkb, Wvp);
    qkproj_kernel<<<dim3(64, 4, 2), 256, 0, stream>>>(hb, Wqb, bq, Wkb, bk, qb, kb);
    bias_kernel<<<dim3(64, 8), 256, 0, stream>>>(qb, row_emb, col_emb, rowbias, colbias);
    attn_kernel<<<1024, 256, 0, stream>>>(qb, kb, htb, rowbias, colbias, mixedb);
    out_proj_kernel<<<512, 256, 0, stream>>>(mixedb, Wvp, bv, out);
}

// Round 5
// 133.266 us; speedup vs baseline: 1.4679x; 1.4246x over previous
//
#include <hip/hip_runtime.h>
#include <math.h>

typedef __bf16 bf16;
typedef bf16 bf16x2 __attribute__((ext_vector_type(2)));
typedef bf16 bf16x4 __attribute__((ext_vector_type(4)));
typedef bf16 bf16x8 __attribute__((ext_vector_type(8)));
typedef float f32x4 __attribute__((ext_vector_type(4)));

constexpr int CENTER = 31;
// 0.125 (1/sqrt(64)) * log2(e): folds exp->exp2 into the Q scale.
constexpr float QSCALE = 0.125f * 1.4426950408889634f;

static __device__ __forceinline__ unsigned short f2bf_bits(float f) {
    bf16 b = (bf16)f;
    return __builtin_bit_cast(unsigned short, b);
}

static __device__ __forceinline__ float fast_exp2(float x) {
#if __has_builtin(__builtin_amdgcn_exp2f)
    return __builtin_amdgcn_exp2f(x);   // raw v_exp_f32
#else
    return exp2f(x);
#endif
}

// =====================================================================
// Kernel 0: one-shot fp32 -> bf16 conversions (unchanged).
// =====================================================================
__global__ __launch_bounds__(256)
void prep_kernel(const float* __restrict__ hid,
                 const float* __restrict__ Wq, const float* __restrict__ Wk,
                 const float* __restrict__ Wv,
                 bf16* __restrict__ hb, bf16* __restrict__ htb,
                 bf16* __restrict__ Wqb, bf16* __restrict__ Wkb,
                 bf16* __restrict__ Wvp)
{
    __shared__ __attribute__((aligned(16))) bf16 hs[64][72];

    const int t   = threadIdx.x;
    const int blk = blockIdx.x;
    const int b   = blk >> 4, kc = blk & 15;

    {
        int row = t >> 2, c4 = (t & 3) * 16;
        const float4* src = (const float4*)(hid + ((size_t)b * 1024 + kc * 64 + row) * 64 + c4);
        bf16 tmp[16];
        #pragma unroll
        for (int u = 0; u < 4; ++u) {
            float4 v = src[u];
            tmp[4*u+0] = (bf16)v.x; tmp[4*u+1] = (bf16)v.y;
            tmp[4*u+2] = (bf16)v.z; tmp[4*u+3] = (bf16)v.w;
        }
        *(int4*)&hs[row][c4]     = ((int4*)tmp)[0];
        *(int4*)&hs[row][c4 + 8] = ((int4*)tmp)[1];
        bf16* hdst = hb + ((size_t)b * 1024 + kc * 64 + row) * 64 + c4;
        *(int4*)hdst       = ((int4*)tmp)[0];
        *(int4*)(hdst + 8) = ((int4*)tmp)[1];
    }

    {
        int idx = blk * 256 + t;
        if (idx < 8192) {
            float4 vq = ((const float4*)Wq)[idx];
            float4 vk = ((const float4*)Wk)[idx];
            float4 vv = ((const float4*)Wv)[idx];
            ushort4 pq, pk2, pv;
            pq.x = f2bf_bits(vq.x); pq.y = f2bf_bits(vq.y); pq.z = f2bf_bits(vq.z); pq.w = f2bf_bits(vq.w);
            pk2.x = f2bf_bits(vk.x); pk2.y = f2bf_bits(vk.y); pk2.z = f2bf_bits(vk.z); pk2.w = f2bf_bits(vk.w);
            pv.x = f2bf_bits(vv.x); pv.y = f2bf_bits(vv.y); pv.z = f2bf_bits(vv.z); pv.w = f2bf_bits(vv.w);
            ((ushort4*)Wqb)[idx] = pq;
            ((ushort4*)Wkb)[idx] = pk2;
            int c = idx >> 7, o4 = (idx & 127) * 4;
            size_t dst = (size_t)((c >> 4) * 16 + (o4 >> 5)) * 512 + (c & 15) * 32 + (o4 & 31);
            *(ushort4*)(Wvp + dst) = pv;
        }
    }
    __syncthreads();

    {
        int d = t >> 2, p0 = (t & 3) * 16;
        ushort tmp[16];
        #pragma unroll
        for (int i = 0; i < 16; ++i)
            tmp[i] = __builtin_bit_cast(unsigned short, hs[p0 + i][d]);
        bf16* dst = htb + ((size_t)b * 64 + d) * 1024 + kc * 64 + p0;
        *(int4*)dst       = ((int4*)tmp)[0];
        *(int4*)(dst + 8) = ((int4*)tmp)[1];
    }
}

// =====================================================================
// Kernel 1: Q/K projection GEMM via MFMA.
// Q/K split across blockIdx.z (512 blocks, 2/CU).
// =====================================================================
__global__ __launch_bounds__(256)
void qkproj_kernel(const bf16* __restrict__ hb,
                   const bf16* __restrict__ Wqb, const float* __restrict__ bq,
                   const bf16* __restrict__ Wkb, const float* __restrict__ bk,
                   bf16* __restrict__ qb, bf16* __restrict__ kb)
{
    __shared__ __attribute__((aligned(16))) bf16 As[128][72];
    __shared__ __attribute__((aligned(16))) bf16 Bs[128][72];

    const int t  = threadIdx.x;
    const int pt = blockIdx.x;
    const int ot = blockIdx.y;
    const int z  = blockIdx.z;
    const int p0 = pt * 128;
    const int b  = p0 >> 10;

    const bf16* Wb        = z ? Wkb : Wqb;
    const float* bias     = z ? bk : bq;
    bf16* outp            = z ? kb : qb;
    const float scale     = z ? 1.0f : QSCALE;

    {
        int row = t >> 1, ch = (t & 1) * 32;
        const int4* asrc = (const int4*)(hb + (size_t)(p0 + row) * 64 + ch);
        const int4* bsrc = (const int4*)(Wb + (size_t)(ot * 128 + row) * 64 + ch);
        #pragma unroll
        for (int u = 0; u < 4; ++u) {
            *(int4*)&As[row][ch + u * 8] = asrc[u];
            *(int4*)&Bs[row][ch + u * 8] = bsrc[u];
        }
    }
    __syncthreads();

    const int w = t >> 6, ln = t & 63, l15 = ln & 15, quad = ln >> 4;

    bf16x8 a[2][2];
    #pragma unroll
    for (int mt = 0; mt < 2; ++mt) {
        a[mt][0] = *(const bf16x8*)&As[w * 32 + mt * 16 + l15][quad * 8];
        a[mt][1] = *(const bf16x8*)&As[w * 32 + mt * 16 + l15][32 + quad * 8];
    }

    const f32x4 z4 = {0.f, 0.f, 0.f, 0.f};
    f32x4 acc[2][8];
    #pragma unroll
    for (int mt = 0; mt < 2; ++mt)
        #pragma unroll
        for (int nt = 0; nt < 8; ++nt) acc[mt][nt] = z4;

    #pragma unroll
    for (int nt = 0; nt < 8; ++nt) {
        bf16x8 b0 = *(const bf16x8*)&Bs[nt * 16 + l15][quad * 8];
        bf16x8 b1 = *(const bf16x8*)&Bs[nt * 16 + l15][32 + quad * 8];
        #pragma unroll
        for (int mt = 0; mt < 2; ++mt) {
            acc[mt][nt] = __builtin_amdgcn_mfma_f32_16x16x32_bf16(a[mt][0], b0, acc[mt][nt], 0, 0, 0);
            acc[mt][nt] = __builtin_amdgcn_mfma_f32_16x16x32_bf16(a[mt][1], b1, acc[mt][nt], 0, 0, 0);
        }
    }

    #pragma unroll
    for (int nt = 0; nt < 8; ++nt) {
        int o = ot * 128 + nt * 16 + l15;
        float bv = bias[o];
        int hh = o >> 6, d = o & 63;
        #pragma unroll
        for (int mt = 0; mt < 2; ++mt)
            #pragma unroll
            for (int r = 0; r < 4; ++r) {
                int pos = (p0 & 1023) + w * 32 + mt * 16 + quad * 4 + r;
                float val = (acc[mt][nt][r] + bv) * scale;
                outp[(((size_t)b * 8 + hh) * 1024 + pos) * 64 + d] = (bf16)val;
            }
    }
}

// =====================================================================
// Kernel 2: positional-bias precompute via MFMA.
// sg split 8 (512 blocks, 2/CU); u-loop 2. Same math.
// =====================================================================
__global__ __launch_bounds__(256)
void bias_kernel(const bf16* __restrict__ qb,
                 const float* __restrict__ row_emb, const float* __restrict__ col_emb,
                 bf16* __restrict__ rowbias, bf16* __restrict__ colbias)
{
    __shared__ __attribute__((aligned(16))) bf16 embRs[63][40];
    __shared__ __attribute__((aligned(16))) bf16 embCs[63][40];

    const int t  = threadIdx.x;
    const int bh = blockIdx.x;
    const int sg = blockIdx.y;

    for (int i = t; i < 2016; i += 256) embRs[i >> 5][i & 31] = (bf16)row_emb[i];
    for (int i = t; i < 2016; i += 256) embCs[i >> 5][i & 31] = (bf16)col_emb[i];
    __syncthreads();

    const int w = t >> 6, ln = t & 63, l15 = ln & 15, quad = ln >> 4;

    #pragma unroll
    for (int u = 0; u < 2; ++u) {
        int s = sg * 8 + u * 4 + w;
        bool cm = s >= 32;
        int ij = cm ? s - 32 : s;

        bf16x8 a[2];
        #pragma unroll
        for (int mt = 0; mt < 2; ++mt) {
            const bf16* ap = cm
                ? qb + ((size_t)bh * 1024 + (mt * 16 + l15) * 32 + ij) * 64 + 32 + quad * 8
                : qb + ((size_t)bh * 1024 + ij * 32 + mt * 16 + l15) * 64 + quad * 8;
            a[mt] = *(const bf16x8*)ap;
        }
        bf16* ob = cm ? colbias : rowbias;

        #pragma unroll
        for (int nt = 0; nt < 2; ++nt) {
            int erow = nt * 16 + l15 + CENTER - ij;
            bf16x8 bfrag = cm ? *(const bf16x8*)&embCs[erow][quad * 8]
                              : *(const bf16x8*)&embRs[erow][quad * 8];
            #pragma unroll
            for (int mt = 0; mt < 2; ++mt) {
                f32x4 c = {0.f, 0.f, 0.f, 0.f};
                c = __builtin_amdgcn_mfma_f32_16x16x32_bf16(a[mt], bfrag, c, 0, 0, 0);
                #pragma unroll
                for (int r = 0; r < 4; ++r) {
                    int ql = mt * 16 + quad * 4 + r;
                    int qrow = cm ? ql * 32 + ij : ij * 32 + ql;
                    ob[((size_t)bh * 1024 + qrow) * 32 + nt * 16 + l15] = (bf16)c[r];
                }
            }
        }
    }
}

// =====================================================================
// Kernel 3: MFMA flash attention, TRANSPOSED dataflow.
// R5: back to the R1-proven 128-q-row tile (mt=2, grid 512, 2 blocks/CU)
// — halves K re-fetch vs the 64-row split AND doubles per-iter compute
// under each prefetch. Keeps XCD-clustered swizzle (xcd r owns bh in
// [8r,8r+8), 8 q-tiles each; per-XCD working set ~3.1MB < 4MB L2),
// register prefetch, exp2 softmax, setprio.
// =====================================================================
__global__ __launch_bounds__(256, 2)
void attn_kernel(const bf16* __restrict__ qb, const bf16* __restrict__ kb,
                 const bf16* __restrict__ htb,
                 const bf16* __restrict__ rowbias, const bf16* __restrict__ colbias,
                 bf16* __restrict__ mixedb)
{
    __shared__ __attribute__((aligned(16))) bf16 Ks[64][72];
    __shared__ __attribute__((aligned(16))) bf16 Hts[64][72];
    __shared__ __attribute__((aligned(16))) bf16 Pp[4][32][72];

    const int t  = threadIdx.x;
    // XCD-clustered decode: xcd = id%8 = r8; XCD r8 owns bh in [8*r8, 8*r8+8).
    const int id = blockIdx.x;
    const int r8 = id & 7;
    const int g  = id >> 3;          // 0..63
    const int qt = g & 7;
    const int bh = r8 * 8 + (g >> 3);
    const int b  = bh >> 3, h = bh & 7;
    const int q0 = qt * 128;
    const int w = t >> 6, ln = t & 63, l15 = ln & 15, quad = ln >> 4;

    bf16x8 bq_[2][2];
    float  cbv[2][2][4];
    const bf16* rbp[2];
    #pragma unroll
    for (int mt = 0; mt < 2; ++mt) {
        int qrow = q0 + w * 32 + mt * 16 + l15;
        const bf16* qp = qb + ((size_t)bh * 1024 + qrow) * 64;
        bq_[mt][0] = *(const bf16x8*)(qp + quad * 8);
        bq_[mt][1] = *(const bf16x8*)(qp + 32 + quad * 8);
        #pragma unroll
        for (int par = 0; par < 2; ++par) {
            bf16x4 cv = *(const bf16x4*)(colbias + ((size_t)bh * 1024 + qrow) * 32 + par * 16 + quad * 4);
            #pragma unroll
            for (int r = 0; r < 4; ++r) cbv[mt][par][r] = (float)cv[r];
        }
        rbp[mt] = rowbias + ((size_t)bh * 1024 + qrow) * 32;
    }

    const f32x4 z4 = {0.f, 0.f, 0.f, 0.f};
    f32x4 oacc[2][4];
    float lsum[2] = {0.f, 0.f};
    #pragma unroll
    for (int mt = 0; mt < 2; ++mt)
        #pragma unroll
        for (int dt = 0; dt < 4; ++dt) oacc[mt][dt] = z4;

    bf16* Pw = &Pp[w][0][0];
    const bf16* kcbase = kb + (size_t)bh * 1024 * 64;
    const bf16* hcbase = htb + (size_t)b * 64 * 1024;

    // Per-thread staging addresses (fixed across kc).
    const int srow = t >> 2, sc = (t & 3) << 4;
    const bf16* kptr = kcbase + (size_t)srow * 64 + sc;     // + kc*4096
    const bf16* hptr = hcbase + (size_t)srow * 1024 + sc;   // + kc*64

    // ---- Prologue: prefetch tile kc=0 into registers ----
    int4 kr0 = *(const int4*)(kptr);
    int4 kr1 = *(const int4*)(kptr + 8);
    int4 hr0 = *(const int4*)(hptr);
    int4 hr1 = *(const int4*)(hptr + 8);
    bf16x2 rnext[2];
    #pragma unroll
    for (int mt = 0; mt < 2; ++mt) rnext[mt] = *(const bf16x2*)(rbp[mt]);

    for (int kc = 0; kc < 16; ++kc) {
        __syncthreads();                       // prior compute done reading LDS
        // ---- Commit prefetched registers to LDS ----
        *(int4*)&Ks[srow][sc]      = kr0;
        *(int4*)&Ks[srow][sc + 8]  = kr1;
        *(int4*)&Hts[srow][sc]     = hr0;
        *(int4*)&Hts[srow][sc + 8] = hr1;
        float rb[2][2];
        #pragma unroll
        for (int mt = 0; mt < 2; ++mt) {
            rb[mt][0] = (float)rnext[mt][0];
            rb[mt][1] = (float)rnext[mt][1];
        }
        __syncthreads();                       // tile kc ready

        // ---- Issue prefetch for tile kc+1 (hides under compute below) ----
        if (kc < 15) {
            const bf16* kn = kptr + (size_t)(kc + 1) * 4096;
            const bf16* hn = hptr + (size_t)(kc + 1) * 64;
            kr0 = *(const int4*)(kn);
            kr1 = *(const int4*)(kn + 8);
            hr0 = *(const int4*)(hn);
            hr1 = *(const int4*)(hn + 8);
            #pragma unroll
            for (int mt = 0; mt < 2; ++mt)
                rnext[mt] = *(const bf16x2*)(rbp[mt] + (kc + 1) * 2);
        }

        // ---- S^T = K . Q^T ----
        f32x4 sf[2][4];
        #pragma unroll
        for (int mt = 0; mt < 2; ++mt)
            #pragma unroll
            for (int kt = 0; kt < 4; ++kt) sf[mt][kt] = z4;
        __builtin_amdgcn_s_setprio(1);
        #pragma unroll
        for (int kt = 0; kt < 4; ++kt) {
            bf16x8 aK0 = *(const bf16x8*)&Ks[kt * 16 + l15][quad * 8];
            bf16x8 aK1 = *(const bf16x8*)&Ks[kt * 16 + l15][32 + quad * 8];
            #pragma unroll
            for (int mt = 0; mt < 2; ++mt) {
                sf[mt][kt] = __builtin_amdgcn_mfma_f32_16x16x32_bf16(aK0, bq_[mt][0], sf[mt][kt], 0, 0, 0);
                sf[mt][kt] = __builtin_amdgcn_mfma_f32_16x16x32_bf16(aK1, bq_[mt][1], sf[mt][kt], 0, 0, 0);
            }
        }
        __builtin_amdgcn_s_setprio(0);

        // ---- softmax numerator: P = exp2(S + rb + cb) ----
        #pragma unroll
        for (int mt = 0; mt < 2; ++mt)
            #pragma unroll
            for (int kt = 0; kt < 4; ++kt) {
                float rbv = rb[mt][kt >> 1];
                ushort4 pk;
                float p0 = fast_exp2(sf[mt][kt][0] + rbv + cbv[mt][kt & 1][0]);
                float p1 = fast_exp2(sf[mt][kt][1] + rbv + cbv[mt][kt & 1][1]);
                float p2 = fast_exp2(sf[mt][kt][2] + rbv + cbv[mt][kt & 1][2]);
                float p3 = fast_exp2(sf[mt][kt][3] + rbv + cbv[mt][kt & 1][3]);
                lsum[mt] += (p0 + p1) + (p2 + p3);
                pk.x = f2bf_bits(p0); pk.y = f2bf_bits(p1);
                pk.z = f2bf_bits(p2); pk.w = f2bf_bits(p3);
                *(ushort4*)&Pw[(mt * 16 + l15) * 72 + kt * 16 + quad * 4] = pk;
            }

        // ---- O^T += Ht . P^T ----
        bf16x8 bp[2][2];
        #pragma unroll
        for (int mt = 0; mt < 2; ++mt) {
            bp[mt][0] = *(const bf16x8*)&Pw[(mt * 16 + l15) * 72 + quad * 8];
            bp[mt][1] = *(const bf16x8*)&Pw[(mt * 16 + l15) * 72 + 32 + quad * 8];
        }
        __builtin_amdgcn_s_setprio(1);
        #pragma unroll
        for (int dt = 0; dt < 4; ++dt) {
            bf16x8 aH0 = *(const bf16x8*)&Hts[dt * 16 + l15][quad * 8];
            bf16x8 aH1 = *(const bf16x8*)&Hts[dt * 16 + l15][32 + quad * 8];
            #pragma unroll
            for (int mt = 0; mt < 2; ++mt) {
                oacc[mt][dt] = __builtin_amdgcn_mfma_f32_16x16x32_bf16(aH0, bp[mt][0], oacc[mt][dt], 0, 0, 0);
                oacc[mt][dt] = __builtin_amdgcn_mfma_f32_16x16x32_bf16(aH1, bp[mt][1], oacc[mt][dt], 0, 0, 0);
            }
        }
        __builtin_amdgcn_s_setprio(0);
    }

    float inv[2];
    #pragma unroll
    for (int mt = 0; mt < 2; ++mt) {
        float v = lsum[mt];
        v += __shfl_xor(v, 16);
        v += __shfl_xor(v, 32);
        inv[mt] = 1.0f / v;
    }
    #pragma unroll
    for (int mt = 0; mt < 2; ++mt) {
        int pos = q0 + w * 32 + mt * 16 + l15;
        bf16* mb = mixedb + ((size_t)b * 1024 + pos) * 512 + h * 64;
        #pragma unroll
        for (int dt = 0; dt < 4; ++dt) {
            ushort4 pk;
            pk.x = f2bf_bits(oacc[mt][dt][0] * inv[mt]);
            pk.y = f2bf_bits(oacc[mt][dt][1] * inv[mt]);
            pk.z = f2bf_bits(oacc[mt][dt][2] * inv[mt]);
            pk.w = f2bf_bits(oacc[mt][dt][3] * inv[mt]);
            *(ushort4*)(mb + dt * 16 + quad * 4) = pk;
        }
    }
}

// =====================================================================
// Kernel 4: output projection via MFMA — zero LDS, zero barriers.
// 16-pos blocks -> 512 blocks (2/CU); single row-tile per wave.
// =====================================================================
__global__ __launch_bounds__(256)
void out_proj_kernel(const bf16* __restrict__ mixedb,
                     const bf16* __restrict__ Wvp, const float* __restrict__ bv,
                     float* __restrict__ out)
{
    const int t  = threadIdx.x;
    const int p0 = blockIdx.x * 16;
    const int w = t >> 6, ln = t & 63, l15 = ln & 15, quad = ln >> 4;

    float bvv = bv[w * 16 + l15];
    f32x4 acc = {bvv, bvv, bvv, bvv};

    const bf16* arow  = mixedb + (size_t)(p0 + l15) * 512 + quad * 8;
    const bf16* bbase = Wvp + (size_t)w * 16 * 512 + l15 * 32 + quad * 8;

    #pragma unroll
    for (int kc = 0; kc < 16; ++kc) {
        bf16x8 a0 = *(const bf16x8*)(arow + kc * 32);
        bf16x8 bfrag = *(const bf16x8*)(bbase + kc * 512);
        acc = __builtin_amdgcn_mfma_f32_16x16x32_bf16(a0, bfrag, acc, 0, 0, 0);
    }

    #pragma unroll
    for (int r = 0; r < 4; ++r)
        out[(size_t)(p0 + quad * 4 + r) * 64 + w * 16 + l15] = acc[r];
}

// =====================================================================
extern "C" void kernel_launch(void* const* d_in, const int* in_sizes, int n_in,
                              void* d_out, int out_size, void* d_ws, size_t ws_size,
                              hipStream_t stream)
{
    const float* hid     = (const float*)d_in[0];
    const float* row_emb = (const float*)d_in[1];
    const float* col_emb = (const float*)d_in[2];
    const float* Wq      = (const float*)d_in[3];
    const float* bq      = (const float*)d_in[4];
    const float* Wk      = (const float*)d_in[5];
    const float* bk      = (const float*)d_in[6];
    const float* Wv      = (const float*)d_in[7];
    const float* bv      = (const float*)d_in[8];
    float* out = (float*)d_out;

    bf16* qb      = (bf16*)d_ws;
    bf16* kb      = qb + (size_t)64 * 1024 * 64;
    bf16* htb     = kb + (size_t)64 * 1024 * 64;
    bf16* rowbias = htb + (size_t)8 * 64 * 1024;
    bf16* colbias = rowbias + (size_t)64 * 1024 * 32;
    bf16* mixedb  = colbias + (size_t)64 * 1024 * 32;
    bf16* hb      = mixedb + (size_t)8 * 1024 * 512;
    bf16* Wqb     = hb + (size_t)8 * 1024 * 64;
    bf16* Wkb     = Wqb + (size_t)512 * 64;
    bf16* Wvp     = Wkb + (size_t)512 * 64;

    prep_kernel<<<128, 256, 0, stream>>>(hid, Wq, Wk, Wv, hb, htb, Wqb, Wkb, Wvp);
    qkproj_kernel<<<dim3(64, 4, 2), 256, 0, stream>>>(hb, Wqb, bq, Wkb, bk, qb, kb);
    bias_kernel<<<dim3(64, 8), 256, 0, stream>>>(qb, row_emb, col_emb, rowbias, colbias);
    attn_kernel<<<512, 256, 0, stream>>>(qb, kb, htb, rowbias, colbias, mixedb);
    out_proj_kernel<<<512, 256, 0, stream>>>(mixedb, Wvp, bv, out);
}

// Round 6
// 131.287 us; speedup vs baseline: 1.4900x; 1.0151x over previous
//
#include <hip/hip_runtime.h>
#include <math.h>

typedef __bf16 bf16;
typedef bf16 bf16x2 __attribute__((ext_vector_type(2)));
typedef bf16 bf16x4 __attribute__((ext_vector_type(4)));
typedef bf16 bf16x8 __attribute__((ext_vector_type(8)));
typedef float f32x4 __attribute__((ext_vector_type(4)));

constexpr int CENTER = 31;
// 0.125 (1/sqrt(64)) * log2(e): folds exp->exp2 into the Q scale.
constexpr float QSCALE = 0.125f * 1.4426950408889634f;

static __device__ __forceinline__ unsigned short f2bf_bits(float f) {
    bf16 b = (bf16)f;
    return __builtin_bit_cast(unsigned short, b);
}

static __device__ __forceinline__ float fast_exp2(float x) {
#if __has_builtin(__builtin_amdgcn_exp2f)
    return __builtin_amdgcn_exp2f(x);   // raw v_exp_f32
#else
    return exp2f(x);
#endif
}

// =====================================================================
// Kernel 0: one-shot fp32 -> bf16 conversions (unchanged).
// =====================================================================
__global__ __launch_bounds__(256)
void prep_kernel(const float* __restrict__ hid,
                 const float* __restrict__ Wq, const float* __restrict__ Wk,
                 const float* __restrict__ Wv,
                 bf16* __restrict__ hb, bf16* __restrict__ htb,
                 bf16* __restrict__ Wqb, bf16* __restrict__ Wkb,
                 bf16* __restrict__ Wvp)
{
    __shared__ __attribute__((aligned(16))) bf16 hs[64][72];

    const int t   = threadIdx.x;
    const int blk = blockIdx.x;
    const int b   = blk >> 4, kc = blk & 15;

    {
        int row = t >> 2, c4 = (t & 3) * 16;
        const float4* src = (const float4*)(hid + ((size_t)b * 1024 + kc * 64 + row) * 64 + c4);
        bf16 tmp[16];
        #pragma unroll
        for (int u = 0; u < 4; ++u) {
            float4 v = src[u];
            tmp[4*u+0] = (bf16)v.x; tmp[4*u+1] = (bf16)v.y;
            tmp[4*u+2] = (bf16)v.z; tmp[4*u+3] = (bf16)v.w;
        }
        *(int4*)&hs[row][c4]     = ((int4*)tmp)[0];
        *(int4*)&hs[row][c4 + 8] = ((int4*)tmp)[1];
        bf16* hdst = hb + ((size_t)b * 1024 + kc * 64 + row) * 64 + c4;
        *(int4*)hdst       = ((int4*)tmp)[0];
        *(int4*)(hdst + 8) = ((int4*)tmp)[1];
    }

    {
        int idx = blk * 256 + t;
        if (idx < 8192) {
            float4 vq = ((const float4*)Wq)[idx];
            float4 vk = ((const float4*)Wk)[idx];
            float4 vv = ((const float4*)Wv)[idx];
            ushort4 pq, pk2, pv;
            pq.x = f2bf_bits(vq.x); pq.y = f2bf_bits(vq.y); pq.z = f2bf_bits(vq.z); pq.w = f2bf_bits(vq.w);
            pk2.x = f2bf_bits(vk.x); pk2.y = f2bf_bits(vk.y); pk2.z = f2bf_bits(vk.z); pk2.w = f2bf_bits(vk.w);
            pv.x = f2bf_bits(vv.x); pv.y = f2bf_bits(vv.y); pv.z = f2bf_bits(vv.z); pv.w = f2bf_bits(vv.w);
            ((ushort4*)Wqb)[idx] = pq;
            ((ushort4*)Wkb)[idx] = pk2;
            int c = idx >> 7, o4 = (idx & 127) * 4;
            size_t dst = (size_t)((c >> 4) * 16 + (o4 >> 5)) * 512 + (c & 15) * 32 + (o4 & 31);
            *(ushort4*)(Wvp + dst) = pv;
        }
    }
    __syncthreads();

    {
        int d = t >> 2, p0 = (t & 3) * 16;
        ushort tmp[16];
        #pragma unroll
        for (int i = 0; i < 16; ++i)
            tmp[i] = __builtin_bit_cast(unsigned short, hs[p0 + i][d]);
        bf16* dst = htb + ((size_t)b * 64 + d) * 1024 + kc * 64 + p0;
        *(int4*)dst       = ((int4*)tmp)[0];
        *(int4*)(dst + 8) = ((int4*)tmp)[1];
    }
}

// =====================================================================
// Kernel 1: Q/K projection GEMM via MFMA.
// Q/K split across blockIdx.z (512 blocks, 2/CU).
// =====================================================================
__global__ __launch_bounds__(256)
void qkproj_kernel(const bf16* __restrict__ hb,
                   const bf16* __restrict__ Wqb, const float* __restrict__ bq,
                   const bf16* __restrict__ Wkb, const float* __restrict__ bk,
                   bf16* __restrict__ qb, bf16* __restrict__ kb)
{
    __shared__ __attribute__((aligned(16))) bf16 As[128][72];
    __shared__ __attribute__((aligned(16))) bf16 Bs[128][72];

    const int t  = threadIdx.x;
    const int pt = blockIdx.x;
    const int ot = blockIdx.y;
    const int z  = blockIdx.z;
    const int p0 = pt * 128;
    const int b  = p0 >> 10;

    const bf16* Wb        = z ? Wkb : Wqb;
    const float* bias     = z ? bk : bq;
    bf16* outp            = z ? kb : qb;
    const float scale     = z ? 1.0f : QSCALE;

    {
        int row = t >> 1, ch = (t & 1) * 32;
        const int4* asrc = (const int4*)(hb + (size_t)(p0 + row) * 64 + ch);
        const int4* bsrc = (const int4*)(Wb + (size_t)(ot * 128 + row) * 64 + ch);
        #pragma unroll
        for (int u = 0; u < 4; ++u) {
            *(int4*)&As[row][ch + u * 8] = asrc[u];
            *(int4*)&Bs[row][ch + u * 8] = bsrc[u];
        }
    }
    __syncthreads();

    const int w = t >> 6, ln = t & 63, l15 = ln & 15, quad = ln >> 4;

    bf16x8 a[2][2];
    #pragma unroll
    for (int mt = 0; mt < 2; ++mt) {
        a[mt][0] = *(const bf16x8*)&As[w * 32 + mt * 16 + l15][quad * 8];
        a[mt][1] = *(const bf16x8*)&As[w * 32 + mt * 16 + l15][32 + quad * 8];
    }

    const f32x4 z4 = {0.f, 0.f, 0.f, 0.f};
    f32x4 acc[2][8];
    #pragma unroll
    for (int mt = 0; mt < 2; ++mt)
        #pragma unroll
        for (int nt = 0; nt < 8; ++nt) acc[mt][nt] = z4;

    #pragma unroll
    for (int nt = 0; nt < 8; ++nt) {
        bf16x8 b0 = *(const bf16x8*)&Bs[nt * 16 + l15][quad * 8];
        bf16x8 b1 = *(const bf16x8*)&Bs[nt * 16 + l15][32 + quad * 8];
        #pragma unroll
        for (int mt = 0; mt < 2; ++mt) {
            acc[mt][nt] = __builtin_amdgcn_mfma_f32_16x16x32_bf16(a[mt][0], b0, acc[mt][nt], 0, 0, 0);
            acc[mt][nt] = __builtin_amdgcn_mfma_f32_16x16x32_bf16(a[mt][1], b1, acc[mt][nt], 0, 0, 0);
        }
    }

    #pragma unroll
    for (int nt = 0; nt < 8; ++nt) {
        int o = ot * 128 + nt * 16 + l15;
        float bv = bias[o];
        int hh = o >> 6, d = o & 63;
        #pragma unroll
        for (int mt = 0; mt < 2; ++mt)
            #pragma unroll
            for (int r = 0; r < 4; ++r) {
                int pos = (p0 & 1023) + w * 32 + mt * 16 + quad * 4 + r;
                float val = (acc[mt][nt][r] + bv) * scale;
                outp[(((size_t)b * 8 + hh) * 1024 + pos) * 64 + d] = (bf16)val;
            }
    }
}

// =====================================================================
// Kernel 2: positional-bias precompute via MFMA.
// sg split 8 (512 blocks, 2/CU); u-loop 2. Same math.
// =====================================================================
__global__ __launch_bounds__(256)
void bias_kernel(const bf16* __restrict__ qb,
                 const float* __restrict__ row_emb, const float* __restrict__ col_emb,
                 bf16* __restrict__ rowbias, bf16* __restrict__ colbias)
{
    __shared__ __attribute__((aligned(16))) bf16 embRs[63][40];
    __shared__ __attribute__((aligned(16))) bf16 embCs[63][40];

    const int t  = threadIdx.x;
    const int bh = blockIdx.x;
    const int sg = blockIdx.y;

    for (int i = t; i < 2016; i += 256) embRs[i >> 5][i & 31] = (bf16)row_emb[i];
    for (int i = t; i < 2016; i += 256) embCs[i >> 5][i & 31] = (bf16)col_emb[i];
    __syncthreads();

    const int w = t >> 6, ln = t & 63, l15 = ln & 15, quad = ln >> 4;

    #pragma unroll
    for (int u = 0; u < 2; ++u) {
        int s = sg * 8 + u * 4 + w;
        bool cm = s >= 32;
        int ij = cm ? s - 32 : s;

        bf16x8 a[2];
        #pragma unroll
        for (int mt = 0; mt < 2; ++mt) {
            const bf16* ap = cm
                ? qb + ((size_t)bh * 1024 + (mt * 16 + l15) * 32 + ij) * 64 + 32 + quad * 8
                : qb + ((size_t)bh * 1024 + ij * 32 + mt * 16 + l15) * 64 + quad * 8;
            a[mt] = *(const bf16x8*)ap;
        }
        bf16* ob = cm ? colbias : rowbias;

        #pragma unroll
        for (int nt = 0; nt < 2; ++nt) {
            int erow = nt * 16 + l15 + CENTER - ij;
            bf16x8 bfrag = cm ? *(const bf16x8*)&embCs[erow][quad * 8]
                              : *(const bf16x8*)&embRs[erow][quad * 8];
            #pragma unroll
            for (int mt = 0; mt < 2; ++mt) {
                f32x4 c = {0.f, 0.f, 0.f, 0.f};
                c = __builtin_amdgcn_mfma_f32_16x16x32_bf16(a[mt], bfrag, c, 0, 0, 0);
                #pragma unroll
                for (int r = 0; r < 4; ++r) {
                    int ql = mt * 16 + quad * 4 + r;
                    int qrow = cm ? ql * 32 + ij : ij * 32 + ql;
                    ob[((size_t)bh * 1024 + qrow) * 32 + nt * 16 + l15] = (bf16)c[r];
                }
            }
        }
    }
}

// =====================================================================
// Kernel 3: MFMA flash attention, TRANSPOSED dataflow.
// R6: LDS DOUBLE-BUFFER, one barrier per kc-iteration (was 2).
//   At iter kc: commit regs(tile kc+1)->buf[cur^1] (overlaps compute),
//   issue loads kc+2->regs, compute tile kc from buf[cur], barrier.
//   Commit<->compute separation on each buffer is 2 iterations -> single
//   barrier is sufficient. LDS 55KB, 2 blocks/CU.
// Keeps: 128-q-row tile, XCD-clustered swizzle, exp2 softmax, setprio.
// =====================================================================
__global__ __launch_bounds__(256, 2)
void attn_kernel(const bf16* __restrict__ qb, const bf16* __restrict__ kb,
                 const bf16* __restrict__ htb,
                 const bf16* __restrict__ rowbias, const bf16* __restrict__ colbias,
                 bf16* __restrict__ mixedb)
{
    __shared__ __attribute__((aligned(16))) bf16 Ks[2][64][72];
    __shared__ __attribute__((aligned(16))) bf16 Hts[2][64][72];
    __shared__ __attribute__((aligned(16))) bf16 Pp[4][32][72];

    const int t  = threadIdx.x;
    // XCD-clustered decode: xcd = id%8 = r8; XCD r8 owns bh in [8*r8, 8*r8+8).
    const int id = blockIdx.x;
    const int r8 = id & 7;
    const int g  = id >> 3;          // 0..63
    const int qt = g & 7;
    const int bh = r8 * 8 + (g >> 3);
    const int b  = bh >> 3, h = bh & 7;
    const int q0 = qt * 128;
    const int w = t >> 6, ln = t & 63, l15 = ln & 15, quad = ln >> 4;

    bf16x8 bq_[2][2];
    float  cbv[2][2][4];
    const bf16* rbp[2];
    #pragma unroll
    for (int mt = 0; mt < 2; ++mt) {
        int qrow = q0 + w * 32 + mt * 16 + l15;
        const bf16* qp = qb + ((size_t)bh * 1024 + qrow) * 64;
        bq_[mt][0] = *(const bf16x8*)(qp + quad * 8);
        bq_[mt][1] = *(const bf16x8*)(qp + 32 + quad * 8);
        #pragma unroll
        for (int par = 0; par < 2; ++par) {
            bf16x4 cv = *(const bf16x4*)(colbias + ((size_t)bh * 1024 + qrow) * 32 + par * 16 + quad * 4);
            #pragma unroll
            for (int r = 0; r < 4; ++r) cbv[mt][par][r] = (float)cv[r];
        }
        rbp[mt] = rowbias + ((size_t)bh * 1024 + qrow) * 32;
    }

    const f32x4 z4 = {0.f, 0.f, 0.f, 0.f};
    f32x4 oacc[2][4];
    float lsum[2] = {0.f, 0.f};
    #pragma unroll
    for (int mt = 0; mt < 2; ++mt)
        #pragma unroll
        for (int dt = 0; dt < 4; ++dt) oacc[mt][dt] = z4;

    bf16* Pw = &Pp[w][0][0];
    const bf16* kcbase = kb + (size_t)bh * 1024 * 64;
    const bf16* hcbase = htb + (size_t)b * 64 * 1024;

    // Per-thread staging addresses (fixed across kc).
    const int srow = t >> 2, sc = (t & 3) << 4;
    const bf16* kptr = kcbase + (size_t)srow * 64 + sc;     // + kc*4096
    const bf16* hptr = hcbase + (size_t)srow * 1024 + sc;   // + kc*64

    // ---- Prologue ----
    // tile0 -> regs -> buf0; tile1 -> regs; barrier.
    int4 kr0 = *(const int4*)(kptr);
    int4 kr1 = *(const int4*)(kptr + 8);
    int4 hr0 = *(const int4*)(hptr);
    int4 hr1 = *(const int4*)(hptr + 8);
    *(int4*)&Ks[0][srow][sc]       = kr0;
    *(int4*)&Ks[0][srow][sc + 8]   = kr1;
    *(int4*)&Hts[0][srow][sc]      = hr0;
    *(int4*)&Hts[0][srow][sc + 8]  = hr1;
    kr0 = *(const int4*)(kptr + 4096);
    kr1 = *(const int4*)(kptr + 4096 + 8);
    hr0 = *(const int4*)(hptr + 64);
    hr1 = *(const int4*)(hptr + 64 + 8);
    bf16x2 rnext[2];
    #pragma unroll
    for (int mt = 0; mt < 2; ++mt) rnext[mt] = *(const bf16x2*)(rbp[mt]);
    __syncthreads();

    int cur = 0;
    for (int kc = 0; kc < 16; ++kc) {
        // ---- Commit regs (tile kc+1) into the other buffer; overlaps compute ----
        if (kc < 15) {
            *(int4*)&Ks[cur ^ 1][srow][sc]      = kr0;
            *(int4*)&Ks[cur ^ 1][srow][sc + 8]  = kr1;
            *(int4*)&Hts[cur ^ 1][srow][sc]     = hr0;
            *(int4*)&Hts[cur ^ 1][srow][sc + 8] = hr1;
        }
        float rb[2][2];
        #pragma unroll
        for (int mt = 0; mt < 2; ++mt) {
            rb[mt][0] = (float)rnext[mt][0];
            rb[mt][1] = (float)rnext[mt][1];
        }
        // ---- Issue loads for tile kc+2 ----
        if (kc < 14) {
            const bf16* kn = kptr + (size_t)(kc + 2) * 4096;
            const bf16* hn = hptr + (size_t)(kc + 2) * 64;
            kr0 = *(const int4*)(kn);
            kr1 = *(const int4*)(kn + 8);
            hr0 = *(const int4*)(hn);
            hr1 = *(const int4*)(hn + 8);
        }
        if (kc < 15) {
            #pragma unroll
            for (int mt = 0; mt < 2; ++mt)
                rnext[mt] = *(const bf16x2*)(rbp[mt] + (kc + 1) * 2);
        }

        // ---- S^T = K . Q^T (from buf[cur]) ----
        const bf16 (* __restrict__ Kc)[72]  = Ks[cur];
        const bf16 (* __restrict__ Hc)[72]  = Hts[cur];
        f32x4 sf[2][4];
        #pragma unroll
        for (int mt = 0; mt < 2; ++mt)
            #pragma unroll
            for (int kt = 0; kt < 4; ++kt) sf[mt][kt] = z4;
        __builtin_amdgcn_s_setprio(1);
        #pragma unroll
        for (int kt = 0; kt < 4; ++kt) {
            bf16x8 aK0 = *(const bf16x8*)&Kc[kt * 16 + l15][quad * 8];
            bf16x8 aK1 = *(const bf16x8*)&Kc[kt * 16 + l15][32 + quad * 8];
            #pragma unroll
            for (int mt = 0; mt < 2; ++mt) {
                sf[mt][kt] = __builtin_amdgcn_mfma_f32_16x16x32_bf16(aK0, bq_[mt][0], sf[mt][kt], 0, 0, 0);
                sf[mt][kt] = __builtin_amdgcn_mfma_f32_16x16x32_bf16(aK1, bq_[mt][1], sf[mt][kt], 0, 0, 0);
            }
        }
        __builtin_amdgcn_s_setprio(0);

        // ---- softmax numerator: P = exp2(S + rb + cb) ----
        #pragma unroll
        for (int mt = 0; mt < 2; ++mt)
            #pragma unroll
            for (int kt = 0; kt < 4; ++kt) {
                float rbv = rb[mt][kt >> 1];
                ushort4 pk;
                float p0 = fast_exp2(sf[mt][kt][0] + rbv + cbv[mt][kt & 1][0]);
                float p1 = fast_exp2(sf[mt][kt][1] + rbv + cbv[mt][kt & 1][1]);
                float p2 = fast_exp2(sf[mt][kt][2] + rbv + cbv[mt][kt & 1][2]);
                float p3 = fast_exp2(sf[mt][kt][3] + rbv + cbv[mt][kt & 1][3]);
                lsum[mt] += (p0 + p1) + (p2 + p3);
                pk.x = f2bf_bits(p0); pk.y = f2bf_bits(p1);
                pk.z = f2bf_bits(p2); pk.w = f2bf_bits(p3);
                *(ushort4*)&Pw[(mt * 16 + l15) * 72 + kt * 16 + quad * 4] = pk;
            }

        // ---- O^T += Ht . P^T ----
        bf16x8 bp[2][2];
        #pragma unroll
        for (int mt = 0; mt < 2; ++mt) {
            bp[mt][0] = *(const bf16x8*)&Pw[(mt * 16 + l15) * 72 + quad * 8];
            bp[mt][1] = *(const bf16x8*)&Pw[(mt * 16 + l15) * 72 + 32 + quad * 8];
        }
        __builtin_amdgcn_s_setprio(1);
        #pragma unroll
        for (int dt = 0; dt < 4; ++dt) {
            bf16x8 aH0 = *(const bf16x8*)&Hc[dt * 16 + l15][quad * 8];
            bf16x8 aH1 = *(const bf16x8*)&Hc[dt * 16 + l15][32 + quad * 8];
            #pragma unroll
            for (int mt = 0; mt < 2; ++mt) {
                oacc[mt][dt] = __builtin_amdgcn_mfma_f32_16x16x32_bf16(aH0, bp[mt][0], oacc[mt][dt], 0, 0, 0);
                oacc[mt][dt] = __builtin_amdgcn_mfma_f32_16x16x32_bf16(aH1, bp[mt][1], oacc[mt][dt], 0, 0, 0);
            }
        }
        __builtin_amdgcn_s_setprio(0);

        __syncthreads();     // single barrier: next iter may overwrite buf[cur^1]... 
        cur ^= 1;            // (commit target) and reads buf[cur^1] (just committed)
    }

    float inv[2];
    #pragma unroll
    for (int mt = 0; mt < 2; ++mt) {
        float v = lsum[mt];
        v += __shfl_xor(v, 16);
        v += __shfl_xor(v, 32);
        inv[mt] = 1.0f / v;
    }
    #pragma unroll
    for (int mt = 0; mt < 2; ++mt) {
        int pos = q0 + w * 32 + mt * 16 + l15;
        bf16* mb = mixedb + ((size_t)b * 1024 + pos) * 512 + h * 64;
        #pragma unroll
        for (int dt = 0; dt < 4; ++dt) {
            ushort4 pk;
            pk.x = f2bf_bits(oacc[mt][dt][0] * inv[mt]);
            pk.y = f2bf_bits(oacc[mt][dt][1] * inv[mt]);
            pk.z = f2bf_bits(oacc[mt][dt][2] * inv[mt]);
            pk.w = f2bf_bits(oacc[mt][dt][3] * inv[mt]);
            *(ushort4*)(mb + dt * 16 + quad * 4) = pk;
        }
    }
}

// =====================================================================
// Kernel 4: output projection via MFMA — zero LDS, zero barriers.
// R6: revert to R1-proven 32-pos/256-block shape (halves Wvp re-reads).
// =====================================================================
__global__ __launch_bounds__(256)
void out_proj_kernel(const bf16* __restrict__ mixedb,
                     const bf16* __restrict__ Wvp, const float* __restrict__ bv,
                     float* __restrict__ out)
{
    const int t  = threadIdx.x;
    const int p0 = blockIdx.x * 32;
    const int w = t >> 6, ln = t & 63, l15 = ln & 15, quad = ln >> 4;

    float bvv = bv[w * 16 + l15];
    f32x4 acc[2] = {(f32x4){bvv, bvv, bvv, bvv}, (f32x4){bvv, bvv, bvv, bvv}};

    const bf16* arow0 = mixedb + (size_t)(p0 + l15) * 512 + quad * 8;
    const bf16* arow1 = mixedb + (size_t)(p0 + 16 + l15) * 512 + quad * 8;
    const bf16* bbase = Wvp + (size_t)w * 16 * 512 + l15 * 32 + quad * 8;

    #pragma unroll
    for (int kc = 0; kc < 16; ++kc) {
        bf16x8 a0 = *(const bf16x8*)(arow0 + kc * 32);
        bf16x8 a1 = *(const bf16x8*)(arow1 + kc * 32);
        bf16x8 bfrag = *(const bf16x8*)(bbase + kc * 512);
        acc[0] = __builtin_amdgcn_mfma_f32_16x16x32_bf16(a0, bfrag, acc[0], 0, 0, 0);
        acc[1] = __builtin_amdgcn_mfma_f32_16x16x32_bf16(a1, bfrag, acc[1], 0, 0, 0);
    }

    #pragma unroll
    for (int mt = 0; mt < 2; ++mt)
        #pragma unroll
        for (int r = 0; r < 4; ++r)
            out[(size_t)(p0 + mt * 16 + quad * 4 + r) * 64 + w * 16 + l15] = acc[mt][r];
}

// =====================================================================
extern "C" void kernel_launch(void* const* d_in, const int* in_sizes, int n_in,
                              void* d_out, int out_size, void* d_ws, size_t ws_size,
                              hipStream_t stream)
{
    const float* hid     = (const float*)d_in[0];
    const float* row_emb = (const float*)d_in[1];
    const float* col_emb = (const float*)d_in[2];
    const float* Wq      = (const float*)d_in[3];
    const float* bq      = (const float*)d_in[4];
    const float* Wk      = (const float*)d_in[5];
    const float* bk      = (const float*)d_in[6];
    const float* Wv      = (const float*)d_in[7];
    const float* bv      = (const float*)d_in[8];
    float* out = (float*)d_out;

    bf16* qb      = (bf16*)d_ws;
    bf16* kb      = qb + (size_t)64 * 1024 * 64;
    bf16* htb     = kb + (size_t)64 * 1024 * 64;
    bf16* rowbias = htb + (size_t)8 * 64 * 1024;
    bf16* colbias = rowbias + (size_t)64 * 1024 * 32;
    bf16* mixedb  = colbias + (size_t)64 * 1024 * 32;
    bf16* hb      = mixedb + (size_t)8 * 1024 * 512;
    bf16* Wqb     = hb + (size_t)8 * 1024 * 64;
    bf16* Wkb     = Wqb + (size_t)512 * 64;
    bf16* Wvp     = Wkb + (size_t)512 * 64;

    prep_kernel<<<128, 256, 0, stream>>>(hid, Wq, Wk, Wv, hb, htb, Wqb, Wkb, Wvp);
    qkproj_kernel<<<dim3(64, 4, 2), 256, 0, stream>>>(hb, Wqb, bq, Wkb, bk, qb, kb);
    bias_kernel<<<dim3(64, 8), 256, 0, stream>>>(qb, row_emb, col_emb, rowbias, colbias);
    attn_kernel<<<512, 256, 0, stream>>>(qb, kb, htb, rowbias, colbias, mixedb);
    out_proj_kernel<<<256, 256, 0, stream>>>(mixedb, Wvp, bv, out);
}

// Round 7
// 127.973 us; speedup vs baseline: 1.5286x; 1.0259x over previous
//
#include <hip/hip_runtime.h>
#include <math.h>

typedef __bf16 bf16;
typedef bf16 bf16x2 __attribute__((ext_vector_type(2)));
typedef bf16 bf16x4 __attribute__((ext_vector_type(4)));
typedef bf16 bf16x8 __attribute__((ext_vector_type(8)));
typedef float f32x4 __attribute__((ext_vector_type(4)));

constexpr int CENTER = 31;
// 0.125 (1/sqrt(64)) * log2(e): folds exp->exp2 into the Q scale.
constexpr float QSCALE = 0.125f * 1.4426950408889634f;

static __device__ __forceinline__ unsigned short f2bf_bits(float f) {
    bf16 b = (bf16)f;
    return __builtin_bit_cast(unsigned short, b);
}

static __device__ __forceinline__ float fast_exp2(float x) {
#if __has_builtin(__builtin_amdgcn_exp2f)
    return __builtin_amdgcn_exp2f(x);   // raw v_exp_f32
#else
    return exp2f(x);
#endif
}

// =====================================================================
// Kernel A (R7): FUSED prep + Q/K projection.
//   blocks 0..511  : QK-proj GEMM, fp32->bf16 conversion done inline at
//                    LDS staging (hb/Wqb/Wkb intermediates eliminated).
//   blocks 512..639: htb transpose + Wvp pack (independent of QK part).
// =====================================================================
__global__ __launch_bounds__(256)
void prep_qkproj_kernel(const float* __restrict__ hid,
                        const float* __restrict__ Wq, const float* __restrict__ bq,
                        const float* __restrict__ Wk, const float* __restrict__ bk,
                        const float* __restrict__ Wv,
                        bf16* __restrict__ qb, bf16* __restrict__ kb,
                        bf16* __restrict__ htb, bf16* __restrict__ Wvp)
{
    const int id = blockIdx.x;
    const int t  = threadIdx.x;

    if (id >= 512) {
        // ---------------- prep-lite: htb transpose + Wvp pack ----------------
        __shared__ __attribute__((aligned(16))) bf16 hs[64][72];
        const int pb = id - 512;
        const int b  = pb >> 4, kc = pb & 15;

        {
            int row = t >> 2, c4 = (t & 3) * 16;
            const float4* src = (const float4*)(hid + ((size_t)b * 1024 + kc * 64 + row) * 64 + c4);
            bf16 tmp[16];
            #pragma unroll
            for (int u = 0; u < 4; ++u) {
                float4 v = src[u];
                tmp[4*u+0] = (bf16)v.x; tmp[4*u+1] = (bf16)v.y;
                tmp[4*u+2] = (bf16)v.z; tmp[4*u+3] = (bf16)v.w;
            }
            *(int4*)&hs[row][c4]     = ((int4*)tmp)[0];
            *(int4*)&hs[row][c4 + 8] = ((int4*)tmp)[1];
        }
        {
            int idx = pb * 256 + t;
            if (idx < 8192) {
                float4 vv = ((const float4*)Wv)[idx];
                ushort4 pv;
                pv.x = f2bf_bits(vv.x); pv.y = f2bf_bits(vv.y);
                pv.z = f2bf_bits(vv.z); pv.w = f2bf_bits(vv.w);
                int c = idx >> 7, o4 = (idx & 127) * 4;
                size_t dst = (size_t)((c >> 4) * 16 + (o4 >> 5)) * 512 + (c & 15) * 32 + (o4 & 31);
                *(ushort4*)(Wvp + dst) = pv;
            }
        }
        __syncthreads();
        {
            int d = t >> 2, p0 = (t & 3) * 16;
            ushort tmp[16];
            #pragma unroll
            for (int i = 0; i < 16; ++i)
                tmp[i] = __builtin_bit_cast(unsigned short, hs[p0 + i][d]);
            bf16* dst = htb + ((size_t)b * 64 + d) * 1024 + kc * 64 + p0;
            *(int4*)dst       = ((int4*)tmp)[0];
            *(int4*)(dst + 8) = ((int4*)tmp)[1];
        }
        return;
    }

    // ---------------- QK projection with inline conversion ----------------
    __shared__ __attribute__((aligned(16))) bf16 As[128][72];
    __shared__ __attribute__((aligned(16))) bf16 Bs[128][72];

    const int pt = id & 63;
    const int ot = (id >> 6) & 3;
    const int z  = (id >> 8) & 1;
    const int p0 = pt * 128;
    const int b  = p0 >> 10;

    const float* Wsrc  = z ? Wk : Wq;
    const float* bias  = z ? bk : bq;
    bf16* outp         = z ? kb : qb;
    const float scale  = z ? 1.0f : QSCALE;

    {
        int row = t >> 1, ch = (t & 1) * 32;
        const float4* asrc = (const float4*)(hid + (size_t)(p0 + row) * 64 + ch);
        const float4* bsrc = (const float4*)(Wsrc + (size_t)(ot * 128 + row) * 64 + ch);
        bf16 ta[32], tb[32];
        #pragma unroll
        for (int u = 0; u < 8; ++u) {
            float4 va = asrc[u], vb = bsrc[u];
            ta[4*u+0] = (bf16)va.x; ta[4*u+1] = (bf16)va.y;
            ta[4*u+2] = (bf16)va.z; ta[4*u+3] = (bf16)va.w;
            tb[4*u+0] = (bf16)vb.x; tb[4*u+1] = (bf16)vb.y;
            tb[4*u+2] = (bf16)vb.z; tb[4*u+3] = (bf16)vb.w;
        }
        #pragma unroll
        for (int u = 0; u < 4; ++u) {
            *(int4*)&As[row][ch + u * 8] = ((int4*)ta)[u];
            *(int4*)&Bs[row][ch + u * 8] = ((int4*)tb)[u];
        }
    }
    __syncthreads();

    const int w = t >> 6, ln = t & 63, l15 = ln & 15, quad = ln >> 4;

    bf16x8 a[2][2];
    #pragma unroll
    for (int mt = 0; mt < 2; ++mt) {
        a[mt][0] = *(const bf16x8*)&As[w * 32 + mt * 16 + l15][quad * 8];
        a[mt][1] = *(const bf16x8*)&As[w * 32 + mt * 16 + l15][32 + quad * 8];
    }

    const f32x4 z4 = {0.f, 0.f, 0.f, 0.f};
    f32x4 acc[2][8];
    #pragma unroll
    for (int mt = 0; mt < 2; ++mt)
        #pragma unroll
        for (int nt = 0; nt < 8; ++nt) acc[mt][nt] = z4;

    #pragma unroll
    for (int nt = 0; nt < 8; ++nt) {
        bf16x8 b0 = *(const bf16x8*)&Bs[nt * 16 + l15][quad * 8];
        bf16x8 b1 = *(const bf16x8*)&Bs[nt * 16 + l15][32 + quad * 8];
        #pragma unroll
        for (int mt = 0; mt < 2; ++mt) {
            acc[mt][nt] = __builtin_amdgcn_mfma_f32_16x16x32_bf16(a[mt][0], b0, acc[mt][nt], 0, 0, 0);
            acc[mt][nt] = __builtin_amdgcn_mfma_f32_16x16x32_bf16(a[mt][1], b1, acc[mt][nt], 0, 0, 0);
        }
    }

    #pragma unroll
    for (int nt = 0; nt < 8; ++nt) {
        int o = ot * 128 + nt * 16 + l15;
        float bv = bias[o];
        int hh = o >> 6, d = o & 63;
        #pragma unroll
        for (int mt = 0; mt < 2; ++mt)
            #pragma unroll
            for (int r = 0; r < 4; ++r) {
                int pos = (p0 & 1023) + w * 32 + mt * 16 + quad * 4 + r;
                float val = (acc[mt][nt][r] + bv) * scale;
                outp[(((size_t)b * 8 + hh) * 1024 + pos) * 64 + d] = (bf16)val;
            }
    }
}

// =====================================================================
// Kernel 2: positional-bias precompute via MFMA (unchanged).
// =====================================================================
__global__ __launch_bounds__(256)
void bias_kernel(const bf16* __restrict__ qb,
                 const float* __restrict__ row_emb, const float* __restrict__ col_emb,
                 bf16* __restrict__ rowbias, bf16* __restrict__ colbias)
{
    __shared__ __attribute__((aligned(16))) bf16 embRs[63][40];
    __shared__ __attribute__((aligned(16))) bf16 embCs[63][40];

    const int t  = threadIdx.x;
    const int bh = blockIdx.x;
    const int sg = blockIdx.y;

    for (int i = t; i < 2016; i += 256) embRs[i >> 5][i & 31] = (bf16)row_emb[i];
    for (int i = t; i < 2016; i += 256) embCs[i >> 5][i & 31] = (bf16)col_emb[i];
    __syncthreads();

    const int w = t >> 6, ln = t & 63, l15 = ln & 15, quad = ln >> 4;

    #pragma unroll
    for (int u = 0; u < 2; ++u) {
        int s = sg * 8 + u * 4 + w;
        bool cm = s >= 32;
        int ij = cm ? s - 32 : s;

        bf16x8 a[2];
        #pragma unroll
        for (int mt = 0; mt < 2; ++mt) {
            const bf16* ap = cm
                ? qb + ((size_t)bh * 1024 + (mt * 16 + l15) * 32 + ij) * 64 + 32 + quad * 8
                : qb + ((size_t)bh * 1024 + ij * 32 + mt * 16 + l15) * 64 + quad * 8;
            a[mt] = *(const bf16x8*)ap;
        }
        bf16* ob = cm ? colbias : rowbias;

        #pragma unroll
        for (int nt = 0; nt < 2; ++nt) {
            int erow = nt * 16 + l15 + CENTER - ij;
            bf16x8 bfrag = cm ? *(const bf16x8*)&embCs[erow][quad * 8]
                              : *(const bf16x8*)&embRs[erow][quad * 8];
            #pragma unroll
            for (int mt = 0; mt < 2; ++mt) {
                f32x4 c = {0.f, 0.f, 0.f, 0.f};
                c = __builtin_amdgcn_mfma_f32_16x16x32_bf16(a[mt], bfrag, c, 0, 0, 0);
                #pragma unroll
                for (int r = 0; r < 4; ++r) {
                    int ql = mt * 16 + quad * 4 + r;
                    int qrow = cm ? ql * 32 + ij : ij * 32 + ql;
                    ob[((size_t)bh * 1024 + qrow) * 32 + nt * 16 + l15] = (bf16)c[r];
                }
            }
        }
    }
}

// =====================================================================
// Kernel 3: MFMA flash attention, TRANSPOSED dataflow.
// R7: bias folded into MFMA accumulator INIT (sf starts at rb+cb, QK^T
// accumulates on top) — deletes 64 VALU adds/wave/iter from softmax.
// Keeps: dbuf single-barrier loop, 128-q tile, XCD-clustered swizzle,
// exp2 softmax, setprio.
// =====================================================================
__global__ __launch_bounds__(256, 2)
void attn_kernel(const bf16* __restrict__ qb, const bf16* __restrict__ kb,
                 const bf16* __restrict__ htb,
                 const bf16* __restrict__ rowbias, const bf16* __restrict__ colbias,
                 bf16* __restrict__ mixedb)
{
    __shared__ __attribute__((aligned(16))) bf16 Ks[2][64][72];
    __shared__ __attribute__((aligned(16))) bf16 Hts[2][64][72];
    __shared__ __attribute__((aligned(16))) bf16 Pp[4][32][72];

    const int t  = threadIdx.x;
    const int id = blockIdx.x;
    const int r8 = id & 7;
    const int g  = id >> 3;          // 0..63
    const int qt = g & 7;
    const int bh = r8 * 8 + (g >> 3);
    const int b  = bh >> 3, h = bh & 7;
    const int q0 = qt * 128;
    const int w = t >> 6, ln = t & 63, l15 = ln & 15, quad = ln >> 4;

    bf16x8 bq_[2][2];
    float  cbv[2][2][4];
    const bf16* rbp[2];
    #pragma unroll
    for (int mt = 0; mt < 2; ++mt) {
        int qrow = q0 + w * 32 + mt * 16 + l15;
        const bf16* qp = qb + ((size_t)bh * 1024 + qrow) * 64;
        bq_[mt][0] = *(const bf16x8*)(qp + quad * 8);
        bq_[mt][1] = *(const bf16x8*)(qp + 32 + quad * 8);
        #pragma unroll
        for (int par = 0; par < 2; ++par) {
            bf16x4 cv = *(const bf16x4*)(colbias + ((size_t)bh * 1024 + qrow) * 32 + par * 16 + quad * 4);
            #pragma unroll
            for (int r = 0; r < 4; ++r) cbv[mt][par][r] = (float)cv[r];
        }
        rbp[mt] = rowbias + ((size_t)bh * 1024 + qrow) * 32;
    }

    const f32x4 z4 = {0.f, 0.f, 0.f, 0.f};
    f32x4 oacc[2][4];
    float lsum[2] = {0.f, 0.f};
    #pragma unroll
    for (int mt = 0; mt < 2; ++mt)
        #pragma unroll
        for (int dt = 0; dt < 4; ++dt) oacc[mt][dt] = z4;

    bf16* Pw = &Pp[w][0][0];
    const bf16* kcbase = kb + (size_t)bh * 1024 * 64;
    const bf16* hcbase = htb + (size_t)b * 64 * 1024;

    const int srow = t >> 2, sc = (t & 3) << 4;
    const bf16* kptr = kcbase + (size_t)srow * 64 + sc;     // + kc*4096
    const bf16* hptr = hcbase + (size_t)srow * 1024 + sc;   // + kc*64

    // ---- Prologue: tile0 -> buf0; tile1 -> regs; barrier ----
    int4 kr0 = *(const int4*)(kptr);
    int4 kr1 = *(const int4*)(kptr + 8);
    int4 hr0 = *(const int4*)(hptr);
    int4 hr1 = *(const int4*)(hptr + 8);
    *(int4*)&Ks[0][srow][sc]       = kr0;
    *(int4*)&Ks[0][srow][sc + 8]   = kr1;
    *(int4*)&Hts[0][srow][sc]      = hr0;
    *(int4*)&Hts[0][srow][sc + 8]  = hr1;
    kr0 = *(const int4*)(kptr + 4096);
    kr1 = *(const int4*)(kptr + 4096 + 8);
    hr0 = *(const int4*)(hptr + 64);
    hr1 = *(const int4*)(hptr + 64 + 8);
    bf16x2 rnext[2];
    #pragma unroll
    for (int mt = 0; mt < 2; ++mt) rnext[mt] = *(const bf16x2*)(rbp[mt]);
    __syncthreads();

    int cur = 0;
    for (int kc = 0; kc < 16; ++kc) {
        // ---- Commit regs (tile kc+1) into the other buffer ----
        if (kc < 15) {
            *(int4*)&Ks[cur ^ 1][srow][sc]      = kr0;
            *(int4*)&Ks[cur ^ 1][srow][sc + 8]  = kr1;
            *(int4*)&Hts[cur ^ 1][srow][sc]     = hr0;
            *(int4*)&Hts[cur ^ 1][srow][sc + 8] = hr1;
        }
        float rb[2][2];
        #pragma unroll
        for (int mt = 0; mt < 2; ++mt) {
            rb[mt][0] = (float)rnext[mt][0];
            rb[mt][1] = (float)rnext[mt][1];
        }
        // ---- Issue loads for tile kc+2 ----
        if (kc < 14) {
            const bf16* kn = kptr + (size_t)(kc + 2) * 4096;
            const bf16* hn = hptr + (size_t)(kc + 2) * 64;
            kr0 = *(const int4*)(kn);
            kr1 = *(const int4*)(kn + 8);
            hr0 = *(const int4*)(hn);
            hr1 = *(const int4*)(hn + 8);
        }
        if (kc < 15) {
            #pragma unroll
            for (int mt = 0; mt < 2; ++mt)
                rnext[mt] = *(const bf16x2*)(rbp[mt] + (kc + 1) * 2);
        }

        // ---- S^T = K . Q^T, accumulator pre-seeded with rb+cb ----
        const bf16 (* __restrict__ Kc)[72]  = Ks[cur];
        const bf16 (* __restrict__ Hc)[72]  = Hts[cur];
        f32x4 sf[2][4];
        #pragma unroll
        for (int mt = 0; mt < 2; ++mt)
            #pragma unroll
            for (int kt = 0; kt < 4; ++kt) {
                float rbv = rb[mt][kt >> 1];
                #pragma unroll
                for (int r = 0; r < 4; ++r)
                    sf[mt][kt][r] = rbv + cbv[mt][kt & 1][r];
            }
        __builtin_amdgcn_s_setprio(1);
        #pragma unroll
        for (int kt = 0; kt < 4; ++kt) {
            bf16x8 aK0 = *(const bf16x8*)&Kc[kt * 16 + l15][quad * 8];
            bf16x8 aK1 = *(const bf16x8*)&Kc[kt * 16 + l15][32 + quad * 8];
            #pragma unroll
            for (int mt = 0; mt < 2; ++mt) {
                sf[mt][kt] = __builtin_amdgcn_mfma_f32_16x16x32_bf16(aK0, bq_[mt][0], sf[mt][kt], 0, 0, 0);
                sf[mt][kt] = __builtin_amdgcn_mfma_f32_16x16x32_bf16(aK1, bq_[mt][1], sf[mt][kt], 0, 0, 0);
            }
        }
        __builtin_amdgcn_s_setprio(0);

        // ---- softmax numerator: P = exp2(sf) (bias already inside) ----
        #pragma unroll
        for (int mt = 0; mt < 2; ++mt)
            #pragma unroll
            for (int kt = 0; kt < 4; ++kt) {
                ushort4 pk;
                float p0 = fast_exp2(sf[mt][kt][0]);
                float p1 = fast_exp2(sf[mt][kt][1]);
                float p2 = fast_exp2(sf[mt][kt][2]);
                float p3 = fast_exp2(sf[mt][kt][3]);
                lsum[mt] += (p0 + p1) + (p2 + p3);
                pk.x = f2bf_bits(p0); pk.y = f2bf_bits(p1);
                pk.z = f2bf_bits(p2); pk.w = f2bf_bits(p3);
                *(ushort4*)&Pw[(mt * 16 + l15) * 72 + kt * 16 + quad * 4] = pk;
            }

        // ---- O^T += Ht . P^T ----
        bf16x8 bp[2][2];
        #pragma unroll
        for (int mt = 0; mt < 2; ++mt) {
            bp[mt][0] = *(const bf16x8*)&Pw[(mt * 16 + l15) * 72 + quad * 8];
            bp[mt][1] = *(const bf16x8*)&Pw[(mt * 16 + l15) * 72 + 32 + quad * 8];
        }
        __builtin_amdgcn_s_setprio(1);
        #pragma unroll
        for (int dt = 0; dt < 4; ++dt) {
            bf16x8 aH0 = *(const bf16x8*)&Hc[dt * 16 + l15][quad * 8];
            bf16x8 aH1 = *(const bf16x8*)&Hc[dt * 16 + l15][32 + quad * 8];
            #pragma unroll
            for (int mt = 0; mt < 2; ++mt) {
                oacc[mt][dt] = __builtin_amdgcn_mfma_f32_16x16x32_bf16(aH0, bp[mt][0], oacc[mt][dt], 0, 0, 0);
                oacc[mt][dt] = __builtin_amdgcn_mfma_f32_16x16x32_bf16(aH1, bp[mt][1], oacc[mt][dt], 0, 0, 0);
            }
        }
        __builtin_amdgcn_s_setprio(0);

        __syncthreads();     // single barrier per iteration (dbuf)
        cur ^= 1;
    }

    float inv[2];
    #pragma unroll
    for (int mt = 0; mt < 2; ++mt) {
        float v = lsum[mt];
        v += __shfl_xor(v, 16);
        v += __shfl_xor(v, 32);
        inv[mt] = 1.0f / v;
    }
    #pragma unroll
    for (int mt = 0; mt < 2; ++mt) {
        int pos = q0 + w * 32 + mt * 16 + l15;
        bf16* mb = mixedb + ((size_t)b * 1024 + pos) * 512 + h * 64;
        #pragma unroll
        for (int dt = 0; dt < 4; ++dt) {
            ushort4 pk;
            pk.x = f2bf_bits(oacc[mt][dt][0] * inv[mt]);
            pk.y = f2bf_bits(oacc[mt][dt][1] * inv[mt]);
            pk.z = f2bf_bits(oacc[mt][dt][2] * inv[mt]);
            pk.w = f2bf_bits(oacc[mt][dt][3] * inv[mt]);
            *(ushort4*)(mb + dt * 16 + quad * 4) = pk;
        }
    }
}

// =====================================================================
// Kernel 4: output projection via MFMA — zero LDS, zero barriers.
// =====================================================================
__global__ __launch_bounds__(256)
void out_proj_kernel(const bf16* __restrict__ mixedb,
                     const bf16* __restrict__ Wvp, const float* __restrict__ bv,
                     float* __restrict__ out)
{
    const int t  = threadIdx.x;
    const int p0 = blockIdx.x * 32;
    const int w = t >> 6, ln = t & 63, l15 = ln & 15, quad = ln >> 4;

    float bvv = bv[w * 16 + l15];
    f32x4 acc[2] = {(f32x4){bvv, bvv, bvv, bvv}, (f32x4){bvv, bvv, bvv, bvv}};

    const bf16* arow0 = mixedb + (size_t)(p0 + l15) * 512 + quad * 8;
    const bf16* arow1 = mixedb + (size_t)(p0 + 16 + l15) * 512 + quad * 8;
    const bf16* bbase = Wvp + (size_t)w * 16 * 512 + l15 * 32 + quad * 8;

    #pragma unroll
    for (int kc = 0; kc < 16; ++kc) {
        bf16x8 a0 = *(const bf16x8*)(arow0 + kc * 32);
        bf16x8 a1 = *(const bf16x8*)(arow1 + kc * 32);
        bf16x8 bfrag = *(const bf16x8*)(bbase + kc * 512);
        acc[0] = __builtin_amdgcn_mfma_f32_16x16x32_bf16(a0, bfrag, acc[0], 0, 0, 0);
        acc[1] = __builtin_amdgcn_mfma_f32_16x16x32_bf16(a1, bfrag, acc[1], 0, 0, 0);
    }

    #pragma unroll
    for (int mt = 0; mt < 2; ++mt)
        #pragma unroll
        for (int r = 0; r < 4; ++r)
            out[(size_t)(p0 + mt * 16 + quad * 4 + r) * 64 + w * 16 + l15] = acc[mt][r];
}

// =====================================================================
extern "C" void kernel_launch(void* const* d_in, const int* in_sizes, int n_in,
                              void* d_out, int out_size, void* d_ws, size_t ws_size,
                              hipStream_t stream)
{
    const float* hid     = (const float*)d_in[0];
    const float* row_emb = (const float*)d_in[1];
    const float* col_emb = (const float*)d_in[2];
    const float* Wq      = (const float*)d_in[3];
    const float* bq      = (const float*)d_in[4];
    const float* Wk      = (const float*)d_in[5];
    const float* bk      = (const float*)d_in[6];
    const float* Wv      = (const float*)d_in[7];
    const float* bv      = (const float*)d_in[8];
    float* out = (float*)d_out;

    bf16* qb      = (bf16*)d_ws;
    bf16* kb      = qb + (size_t)64 * 1024 * 64;
    bf16* htb     = kb + (size_t)64 * 1024 * 64;
    bf16* rowbias = htb + (size_t)8 * 64 * 1024;
    bf16* colbias = rowbias + (size_t)64 * 1024 * 32;
    bf16* mixedb  = colbias + (size_t)64 * 1024 * 32;
    bf16* Wvp     = mixedb + (size_t)8 * 1024 * 512;

    prep_qkproj_kernel<<<640, 256, 0, stream>>>(hid, Wq, bq, Wk, bk, Wv, qb, kb, htb, Wvp);
    bias_kernel<<<dim3(64, 8), 256, 0, stream>>>(qb, row_emb, col_emb, rowbias, colbias);
    attn_kernel<<<512, 256, 0, stream>>>(qb, kb, htb, rowbias, colbias, mixedb);
    out_proj_kernel<<<256, 256, 0, stream>>>(mixedb, Wvp, bv, out);
}